// Round 4
// baseline (7909.404 us; speedup 1.0000x reference)
//
#include <hip/hip_runtime.h>
#include <cstddef>

// ---------------------------------------------------------------------------
// CNN(3 conv blocks) -> faithful reshape -> 5-step LSTM -> fc1(relu) -> fc2
// All fp32. Activations channels-last with x-only halo padding.
// Conv chain is chunked over batch (chunk size adapted to ws_size); conv3b
// writes NCDHW so its output IS the LSTM "hidden" matrix (1280x2048).
// LSTM-phase scratch overlaps the conv-phase chunk region (disjoint in time).
// ---------------------------------------------------------------------------

// x chunk: (CB,16,16,32,4) -> xp: (CB,16,16,34,4) with x-halo zeros
__global__ __launch_bounds__(256) void pad_x_kernel(
    const float* __restrict__ x, float* __restrict__ xp, int total)
{
  int e = blockIdx.x * 256 + threadIdx.x;           // one float4 (ic) per thread
  if (e >= total) return;
  int xs = e % 34; int r = e / 34;
  float4 v = make_float4(0.f, 0.f, 0.f, 0.f);
  if (xs >= 1 && xs <= 32) {
    v = *reinterpret_cast<const float4*>(x + ((size_t)r * 32 + (xs - 1)) * 4);
  }
  *reinterpret_cast<float4*>(xp + (size_t)e * 4) = v;
}

// w: (OC,IC,2,3,3) -> wt: (k=kt*9+ky*3+kx, ic, oc), optional scale (folds /255)
__global__ __launch_bounds__(256) void wtrans_kernel(
    const float* __restrict__ w, float* __restrict__ wt,
    int IC, int OC, float scale, int total)
{
  int e = blockIdx.x * 256 + threadIdx.x;
  if (e >= total) return;
  int oc = e % OC; int t = e / OC; int ic = t % IC; int k = t / IC; // k in [0,18)
  int kt = k / 9; int r9 = k % 9; int ky = r9 / 3; int kx = r9 % 3;
  wt[e] = w[((((size_t)oc * IC + ic) * 2 + kt) * 3 + ky) * 3 + kx] * scale;
}

__global__ __launch_bounds__(256) void bsum_kernel(
    const float* __restrict__ a, const float* __restrict__ b, float* __restrict__ o)
{
  int e = blockIdx.x * 256 + threadIdx.x;
  if (e < 2048) o[e] = a[e] + b[e];
}

// ---------------- direct conv (kd=2, 3x3 spatial, pad (0,1,1)) ----------------
// input : (B, Ti, Hi, Wi+2, IC) channels-last, x-halo padded
// output: (B, To, Ho, Wo+2, OC) channels-last, x-halo padded (written here)
//         or NCDHW (B, OC, To, Ho, Wo) when OUT_NCDHW (no halo)
// weights: (18, IC, OC), bias: (OC). ReLU fused. RX outputs along x per thread.
template<int IC, int OC, int SP, int RX, bool OUT_NCDHW>
__global__ __launch_bounds__(256) void conv3d_relu(
    const float* __restrict__ in, const float* __restrict__ wt,
    const float* __restrict__ bias, float* __restrict__ out,
    int B, int Ti, int Hi, int Wi, int To, int Ho, int Wo)
{
  const int WT = Wo / RX;
  long long g = (long long)blockIdx.x * 256 + threadIdx.x;
  const int oc = (int)(g % OC); g /= OC;
  const int xt = (int)(g % WT); g /= WT;
  const int y  = (int)(g % Ho); g /= Ho;
  const int t  = (int)(g % To);
  const int b  = (int)(g / To);
  if (b >= B) return;
  const int xg  = xt * RX;
  const int Wis = Wi + 2;

  float acc[RX];
  const float bv = bias[oc];
  #pragma unroll
  for (int r = 0; r < RX; ++r) acc[r] = bv;

  #pragma unroll
  for (int kt = 0; kt < 2; ++kt) {
    const int it = t + kt;
    #pragma unroll
    for (int ky = 0; ky < 3; ++ky) {
      const int iy = y * SP + ky - 1;
      if (iy < 0 || iy >= Hi) continue;     // wave-uniform: free
      const float* __restrict__ inrow =
          in + (size_t)((b * Ti + it) * Hi + iy) * (size_t)(Wis * IC);
      #pragma unroll
      for (int kx = 0; kx < 3; ++kx) {
        const float* __restrict__ wp =
            wt + (size_t)((kt * 3 + ky) * 3 + kx) * (IC * OC) + oc;
        const float* __restrict__ ip0 = inrow + (size_t)(xg * SP + kx) * IC;
        #pragma unroll 4
        for (int ic4 = 0; ic4 < IC / 4; ++ic4) {
          const float w0 = wp[(ic4 * 4 + 0) * OC];
          const float w1 = wp[(ic4 * 4 + 1) * OC];
          const float w2 = wp[(ic4 * 4 + 2) * OC];
          const float w3 = wp[(ic4 * 4 + 3) * OC];
          #pragma unroll
          for (int r = 0; r < RX; ++r) {
            const float4 v = *reinterpret_cast<const float4*>(
                ip0 + (size_t)(r * SP) * IC + ic4 * 4);
            acc[r] = fmaf(v.x, w0, acc[r]);
            acc[r] = fmaf(v.y, w1, acc[r]);
            acc[r] = fmaf(v.z, w2, acc[r]);
            acc[r] = fmaf(v.w, w3, acc[r]);
          }
        }
      }
    }
  }

  #pragma unroll
  for (int r = 0; r < RX; ++r) acc[r] = fmaxf(acc[r], 0.0f);

  if constexpr (OUT_NCDHW) {
    float* op = out + ((((size_t)b * OC + oc) * To + t) * Ho + y) * Wo + xg;
    #pragma unroll
    for (int r = 0; r < RX; ++r) op[r] = acc[r];
  } else {
    float* op = out + (((size_t)(b * To + t) * Ho + y) * (Wo + 2) + xg + 1) * OC + oc;
    #pragma unroll
    for (int r = 0; r < RX; ++r) op[(size_t)r * OC] = acc[r];
    // write this row's x-halo zeros (ensures downstream reads are clean)
    if (xg == 0)        op[-OC] = 0.0f;             // storage x = 0
    if (xg + RX == Wo)  op[(size_t)RX * OC] = 0.0f; // storage x = Wo+1
  }
}

// ---------------- fp32 tiled GEMM: C = act(A * B^T + D + bias) ----------------
// A: (M,K) row-major, Bm: (N,K) row-major; D: optional (M,N), bias: optional (N).
// M,N multiples of 64; K multiple of 16.
__global__ __launch_bounds__(256) void gemm_nt(
    const float* __restrict__ A, const float* __restrict__ Bm,
    const float* __restrict__ D, const float* __restrict__ bias,
    float* __restrict__ C, int M, int N, int K, int relu)
{
  __shared__ float As[16][68];
  __shared__ float Bs[16][68];
  const int tid = threadIdx.x;
  const int kk = tid & 15, rr = tid >> 4;   // load mapping
  const int tx = tid & 15, ty = tid >> 4;   // compute mapping
  const int m0 = blockIdx.y * 64, n0 = blockIdx.x * 64;

  float acc[4][4];
  #pragma unroll
  for (int i = 0; i < 4; ++i)
    #pragma unroll
    for (int j = 0; j < 4; ++j) acc[i][j] = 0.f;

  for (int k0 = 0; k0 < K; k0 += 16) {
    #pragma unroll
    for (int p = 0; p < 4; ++p) {
      As[kk][rr + p * 16] = A[(size_t)(m0 + rr + p * 16) * K + (k0 + kk)];
      Bs[kk][rr + p * 16] = Bm[(size_t)(n0 + rr + p * 16) * K + (k0 + kk)];
    }
    __syncthreads();
    #pragma unroll
    for (int k = 0; k < 16; ++k) {
      const float4 av = *reinterpret_cast<const float4*>(&As[k][ty * 4]);
      const float4 bv = *reinterpret_cast<const float4*>(&Bs[k][tx * 4]);
      const float a_[4] = {av.x, av.y, av.z, av.w};
      const float b_[4] = {bv.x, bv.y, bv.z, bv.w};
      #pragma unroll
      for (int i = 0; i < 4; ++i)
        #pragma unroll
        for (int j = 0; j < 4; ++j)
          acc[i][j] = fmaf(a_[i], b_[j], acc[i][j]);
    }
    __syncthreads();
  }

  #pragma unroll
  for (int i = 0; i < 4; ++i) {
    const int m = m0 + ty * 4 + i;
    const int n = n0 + tx * 4;
    float4 v = make_float4(acc[i][0], acc[i][1], acc[i][2], acc[i][3]);
    if (D) {
      const float4 d4 = *reinterpret_cast<const float4*>(&D[(size_t)m * N + n]);
      v.x += d4.x; v.y += d4.y; v.z += d4.z; v.w += d4.w;
    }
    if (bias) {
      const float4 b4 = *reinterpret_cast<const float4*>(&bias[n]);
      v.x += b4.x; v.y += b4.y; v.z += b4.z; v.w += b4.w;
    }
    if (relu) {
      v.x = fmaxf(v.x, 0.f); v.y = fmaxf(v.y, 0.f);
      v.z = fmaxf(v.z, 0.f); v.w = fmaxf(v.w, 0.f);
    }
    *reinterpret_cast<float4*>(&C[(size_t)m * N + n]) = v;
  }
}

// ---------------- LSTM elementwise ----------------

__global__ __launch_bounds__(256) void lstm_mask(
    const float* __restrict__ h, const float* __restrict__ c,
    const float* __restrict__ done_l, float* __restrict__ hm, float* __restrict__ cm)
{
  int e = blockIdx.x * 256 + threadIdx.x;
  if (e >= 256 * 512) return;
  const float m = 1.f - done_l[e >> 9];
  hm[e] = h[e] * m;
  cm[e] = c[e] * m;
}

__global__ __launch_bounds__(256) void lstm_cell(
    const float* __restrict__ gates, const float* __restrict__ cm,
    float* __restrict__ hs_l, float* __restrict__ h_buf, float* __restrict__ c_buf,
    float* __restrict__ hT, float* __restrict__ cT)
{
  int e = blockIdx.x * 256 + threadIdx.x;
  if (e >= 256 * 512) return;
  const int b = e >> 9, u = e & 511;
  const float* gr = gates + (size_t)b * 2048;
  float i = gr[u], f = gr[512 + u], g = gr[1024 + u], o = gr[1536 + u];
  i = 1.f / (1.f + expf(-i));
  f = 1.f / (1.f + expf(-f));
  o = 1.f / (1.f + expf(-o));
  g = tanhf(g);
  const float cn = f * cm[e] + i * g;
  const float hn = o * tanhf(cn);
  hs_l[e] = hn; h_buf[e] = hn; c_buf[e] = cn;
  if (hT) { hT[e] = hn; cT[e] = cn; }
}

// logits (1280,5) = z (1280,512) @ fc2_w^T (512,5) + fc2_b
__global__ __launch_bounds__(256) void fc2_kernel(
    const float* __restrict__ z, const float* __restrict__ w,
    const float* __restrict__ b, float* __restrict__ out)
{
  int e = blockIdx.x * 256 + threadIdx.x;
  if (e >= 1280 * 5) return;
  const int n = e % 5, m = e / 5;
  const float* zr = z + (size_t)m * 512;
  const float* wr = w + (size_t)n * 512;
  float acc = b[n];
  for (int k = 0; k < 512; k += 4) {
    const float4 zv = *reinterpret_cast<const float4*>(zr + k);
    const float4 wv = *reinterpret_cast<const float4*>(wr + k);
    acc += zv.x * wv.x + zv.y * wv.y + zv.z * wv.z + zv.w * wv.w;
  }
  out[e] = acc;
}

// ---------------- host ----------------

extern "C" void kernel_launch(void* const* d_in, const int* in_sizes, int n_in,
                              void* d_out, int out_size, void* d_ws, size_t ws_size,
                              hipStream_t stream)
{
  const float* x    = (const float*)d_in[0];
  const float* done = (const float*)d_in[1];
  const float* h0   = (const float*)d_in[2];
  const float* c0   = (const float*)d_in[3];
  const float* w1a = (const float*)d_in[4];  const float* b1a = (const float*)d_in[5];
  const float* w1b = (const float*)d_in[6];  const float* b1b = (const float*)d_in[7];
  const float* w2a = (const float*)d_in[8];  const float* b2a = (const float*)d_in[9];
  const float* w2b = (const float*)d_in[10]; const float* b2b = (const float*)d_in[11];
  const float* w3a = (const float*)d_in[12]; const float* b3a = (const float*)d_in[13];
  const float* w3b = (const float*)d_in[14]; const float* b3b = (const float*)d_in[15];
  const float* W_ih = (const float*)d_in[16];
  const float* W_hh = (const float*)d_in[17];
  const float* b_ih = (const float*)d_in[18];
  const float* b_hh = (const float*)d_in[19];
  const float* fc1w = (const float*)d_in[20]; const float* fc1b = (const float*)d_in[21];
  const float* fc2w = (const float*)d_in[22]; const float* fc2b = (const float*)d_in[23];

  float* ws = (float*)d_ws;
  float* outp = (float*)d_out;
  (void)in_sizes; (void)n_in; (void)out_size;

  // ---------------- workspace layout (floats, all sizes 256-aligned) --------
  size_t off = 0;
  auto alloc = [&off](size_t n) { size_t r = off; off += (n + 255) & ~(size_t)255; return r; };
  // fixed region (lives the whole launch)
  const size_t o_w1a = alloc(18 * 4 * 32);
  const size_t o_w1b = alloc(18 * 32 * 32);
  const size_t o_w2a = alloc(18 * 32 * 64);
  const size_t o_w2b = alloc(18 * 64 * 64);
  const size_t o_w3a = alloc(18 * 64 * 128);
  const size_t o_w3b = alloc(18 * 128 * 128);
  const size_t o_bs  = alloc(2048);
  const size_t o_hid = alloc((size_t)1280 * 2048);  // conv3b out == LSTM input rows
  const size_t o_gx  = alloc((size_t)1280 * 2048);  // x-projection gates
  const size_t o_R   = off;                         // overlapped region start

  // LSTM-phase scratch (used only AFTER the conv chunks are done)
  size_t loff = o_R;
  auto lalloc = [&loff](size_t n) { size_t r = loff; loff += (n + 255) & ~(size_t)255; return r; };
  const size_t o_g  = lalloc((size_t)256 * 2048);
  const size_t o_hm = lalloc(256 * 512);
  const size_t o_cm = lalloc(256 * 512);
  const size_t o_h  = lalloc(256 * 512);
  const size_t o_c  = lalloc(256 * 512);
  const size_t o_hs = lalloc((size_t)1280 * 512);
  const size_t o_z  = lalloc((size_t)1280 * 512);

  // conv-phase chunk scratch (per batch-chunk, ping-pong), also starts at o_R
  const size_t XP_B = 34816;   // 16*16*34*4   (all multiples of 256)
  const size_t A_B  = 261120;  // 15*16*34*32  (max of conv1a/2a/3a outputs)
  const size_t B_B  = 64512;   // 14*8*18*32   (max of conv1b/2b outputs)
  const size_t PER_B = XP_B + A_B + B_B;      // 360448 floats per batch element

  const size_t ws_floats = ws_size / sizeof(float);
  const size_t avail = (ws_floats > o_R) ? (ws_floats - o_R) : 0;
  int CB = 256;
  while (CB > 1 && (size_t)CB * PER_B > avail) CB >>= 1;
  const int nchunks = 256 / CB;

  const size_t o_xp = o_R;
  const size_t o_A  = o_xp + (size_t)CB * XP_B;
  const size_t o_B  = o_A  + (size_t)CB * A_B;

  auto nblk = [](long long n) { return (unsigned)((n + 255) / 256); };

  // ---------------- prep ----------------
  wtrans_kernel<<<nblk(18 * 4 * 32), 256, 0, stream>>>(w1a, ws + o_w1a, 4, 32, 1.f / 255.f, 18 * 4 * 32);
  wtrans_kernel<<<nblk(18 * 32 * 32), 256, 0, stream>>>(w1b, ws + o_w1b, 32, 32, 1.f, 18 * 32 * 32);
  wtrans_kernel<<<nblk(18 * 32 * 64), 256, 0, stream>>>(w2a, ws + o_w2a, 32, 64, 1.f / 255.f, 18 * 32 * 64);
  wtrans_kernel<<<nblk(18 * 64 * 64), 256, 0, stream>>>(w2b, ws + o_w2b, 64, 64, 1.f, 18 * 64 * 64);
  wtrans_kernel<<<nblk(18 * 64 * 128), 256, 0, stream>>>(w3a, ws + o_w3a, 64, 128, 1.f / 255.f, 18 * 64 * 128);
  wtrans_kernel<<<nblk(18 * 128 * 128), 256, 0, stream>>>(w3b, ws + o_w3b, 128, 128, 1.f, 18 * 128 * 128);
  bsum_kernel<<<8, 256, 0, stream>>>(b_ih, b_hh, ws + o_bs);

  // ---------------- conv chain, chunked over batch ----------------
  for (int c = 0; c < nchunks; ++c) {
    const int b0 = c * CB;
    pad_x_kernel<<<nblk((long long)CB * 16 * 16 * 34), 256, 0, stream>>>(
        x + (size_t)b0 * 16 * 16 * 32 * 4, ws + o_xp, CB * 16 * 16 * 34);
    conv3d_relu<4, 32, 1, 4, false><<<nblk((long long)CB * 15 * 16 * 8 * 32), 256, 0, stream>>>(
        ws + o_xp, ws + o_w1a, b1a, ws + o_A, CB, 16, 16, 32, 15, 16, 32);
    conv3d_relu<32, 32, 2, 4, false><<<nblk((long long)CB * 14 * 8 * 4 * 32), 256, 0, stream>>>(
        ws + o_A, ws + o_w1b, b1b, ws + o_B, CB, 15, 16, 32, 14, 8, 16);
    conv3d_relu<32, 64, 1, 4, false><<<nblk((long long)CB * 13 * 8 * 4 * 64), 256, 0, stream>>>(
        ws + o_B, ws + o_w2a, b2a, ws + o_A, CB, 14, 8, 16, 13, 8, 16);
    conv3d_relu<64, 64, 2, 4, false><<<nblk((long long)CB * 12 * 4 * 2 * 64), 256, 0, stream>>>(
        ws + o_A, ws + o_w2b, b2b, ws + o_B, CB, 13, 8, 16, 12, 4, 8);
    conv3d_relu<64, 128, 1, 4, false><<<nblk((long long)CB * 11 * 4 * 2 * 128), 256, 0, stream>>>(
        ws + o_B, ws + o_w3a, b3a, ws + o_A, CB, 12, 4, 8, 11, 4, 8);
    conv3d_relu<128, 128, 2, 4, true><<<nblk((long long)CB * 10 * 2 * 1 * 128), 256, 0, stream>>>(
        ws + o_A, ws + o_w3b, b3b, ws + o_hid + (size_t)b0 * 10240, CB, 11, 4, 8, 10, 2, 4);
  }
  // ws+o_hid now holds "hidden" = (1280, 2048) row-major (faithful reshape free)

  // x-projection for all 5 steps: gatesx = hidden @ W_ih^T + (b_ih + b_hh)
  gemm_nt<<<dim3(2048 / 64, 1280 / 64), 256, 0, stream>>>(
      ws + o_hid, W_ih, nullptr, ws + o_bs, ws + o_gx, 1280, 2048, 2048, 0);

  // ---------------- recurrent steps ----------------
  for (int l = 0; l < 5; ++l) {
    const float* hsrc = (l == 0) ? h0 : ws + o_h;
    const float* csrc = (l == 0) ? c0 : ws + o_c;
    lstm_mask<<<512, 256, 0, stream>>>(hsrc, csrc, done + (size_t)l * 256,
                                       ws + o_hm, ws + o_cm);
    gemm_nt<<<dim3(2048 / 64, 256 / 64), 256, 0, stream>>>(
        ws + o_hm, W_hh, ws + o_gx + (size_t)l * 256 * 2048, nullptr,
        ws + o_g, 256, 2048, 512, 0);
    lstm_cell<<<512, 256, 0, stream>>>(
        ws + o_g, ws + o_cm, ws + o_hs + (size_t)l * 256 * 512, ws + o_h, ws + o_c,
        (l == 4) ? outp + 6400 : nullptr,
        (l == 4) ? outp + 6400 + 256 * 512 : nullptr);
  }

  // ---------------- heads ----------------
  gemm_nt<<<dim3(512 / 64, 1280 / 64), 256, 0, stream>>>(
      ws + o_hs, fc1w, nullptr, fc1b, ws + o_z, 1280, 512, 512, 1);
  fc2_kernel<<<nblk(1280 * 5), 256, 0, stream>>>(ws + o_z, fc2w, fc2b, outp);
}

// Round 5
// 4558.168 us; speedup vs baseline: 1.7352x; 1.7352x over previous
//
#include <hip/hip_runtime.h>
#include <cstddef>

// ---------------------------------------------------------------------------
// CNN(3 conv blocks) -> faithful reshape -> 5-step LSTM -> fc1(relu) -> fc2
// All fp32. Activations channels-last with x-only halo padding.
// Conv chain is chunked over batch (chunk size adapted to ws_size); conv3b
// writes NCDHW so its output IS the LSTM "hidden" matrix (1280x2048).
// LSTM-phase scratch overlaps the conv-phase chunk region (disjoint in time).
// Conv kernel v2: 4-oc x RX-x register tile per thread, input sliding window
// in registers reused across kx taps (FMA:VMEM ~10.7:1, was 2:1).
// ---------------------------------------------------------------------------

// x chunk: (CB,16,16,32,4) -> xp: (CB,16,16,34,4) with x-halo zeros
__global__ __launch_bounds__(256) void pad_x_kernel(
    const float* __restrict__ x, float* __restrict__ xp, int total)
{
  int e = blockIdx.x * 256 + threadIdx.x;           // one float4 (ic) per thread
  if (e >= total) return;
  int xs = e % 34; int r = e / 34;
  float4 v = make_float4(0.f, 0.f, 0.f, 0.f);
  if (xs >= 1 && xs <= 32) {
    v = *reinterpret_cast<const float4*>(x + ((size_t)r * 32 + (xs - 1)) * 4);
  }
  *reinterpret_cast<float4*>(xp + (size_t)e * 4) = v;
}

// w: (OC,IC,2,3,3) -> wt: (k=kt*9+ky*3+kx, ic, oc), optional scale (folds /255)
__global__ __launch_bounds__(256) void wtrans_kernel(
    const float* __restrict__ w, float* __restrict__ wt,
    int IC, int OC, float scale, int total)
{
  int e = blockIdx.x * 256 + threadIdx.x;
  if (e >= total) return;
  int oc = e % OC; int t = e / OC; int ic = t % IC; int k = t / IC; // k in [0,18)
  int kt = k / 9; int r9 = k % 9; int ky = r9 / 3; int kx = r9 % 3;
  wt[e] = w[((((size_t)oc * IC + ic) * 2 + kt) * 3 + ky) * 3 + kx] * scale;
}

__global__ __launch_bounds__(256) void bsum_kernel(
    const float* __restrict__ a, const float* __restrict__ b, float* __restrict__ o)
{
  int e = blockIdx.x * 256 + threadIdx.x;
  if (e < 2048) o[e] = a[e] + b[e];
}

#define FMA4(A, S, W)                  \
  A.x = fmaf((S), (W).x, A.x);         \
  A.y = fmaf((S), (W).y, A.y);         \
  A.z = fmaf((S), (W).z, A.z);         \
  A.w = fmaf((S), (W).w, A.w)

// ---------------- direct conv v2 (kd=2, 3x3 spatial, pad (0,1,1)) -------------
// input : (B, Ti, Hi, Wi+2, IC) channels-last, x-halo padded
// output: (B, To, Ho, Wo+2, OC) channels-last, x-halo padded (written here)
//         or NCDHW (B, OC, To, Ho, Wo) when OUT_NCDHW (no halo)
// weights: (18, IC, OC), bias: (OC). ReLU fused.
// Per thread: RX outputs along x times 4 consecutive oc (float4 accumulators).
// Input window kept in registers across the 3 kx taps.
template<int IC, int OC, int SP, int RX, bool OUT_NCDHW>
__global__ __launch_bounds__(256) void conv3d_relu(
    const float* __restrict__ in, const float* __restrict__ wt,
    const float* __restrict__ bias, float* __restrict__ out,
    int B, int Ti, int Hi, int Wi, int To, int Ho, int Wo)
{
  constexpr int NOC = OC / 4;             // oc-quads
  constexpr int NXW = (RX - 1) * SP + 3;  // input float4s per (kt,ky,ic4) window
  const int WT = Wo / RX;
  long long g = (long long)blockIdx.x * 256 + threadIdx.x;
  const int oc4 = (int)(g % NOC); g /= NOC;
  const int xt  = (int)(g % WT); g /= WT;
  const int y   = (int)(g % Ho); g /= Ho;
  const int t   = (int)(g % To);
  const int b   = (int)(g / To);
  if (b >= B) return;
  const int xg  = xt * RX;
  const int Wis = Wi + 2;

  float4 acc[RX];
  const float4 bv = *reinterpret_cast<const float4*>(bias + oc4 * 4);
  #pragma unroll
  for (int r = 0; r < RX; ++r) acc[r] = bv;

  #pragma unroll
  for (int kt = 0; kt < 2; ++kt) {
    const int it = t + kt;
    #pragma unroll
    for (int ky = 0; ky < 3; ++ky) {
      const int iy = y * SP + ky - 1;
      if (iy < 0 || iy >= Hi) continue;     // wave-uniform: free
      const float* __restrict__ inrow =
          in + (size_t)((b * Ti + it) * Hi + iy) * (size_t)(Wis * IC)
             + (size_t)(xg * SP) * IC;
      #pragma unroll 4
      for (int ic4 = 0; ic4 < IC / 4; ++ic4) {
        // input sliding window: x positions xg*SP + p, p in [0, NXW)
        float4 xv[NXW];
        #pragma unroll
        for (int p = 0; p < NXW; ++p)
          xv[p] = *reinterpret_cast<const float4*>(inrow + (size_t)p * IC + ic4 * 4);
        #pragma unroll
        for (int kx = 0; kx < 3; ++kx) {
          const float* __restrict__ wp =
              wt + ((size_t)((kt * 3 + ky) * 3 + kx) * IC + ic4 * 4) * OC + oc4 * 4;
          const float4 w0 = *reinterpret_cast<const float4*>(wp);
          const float4 w1 = *reinterpret_cast<const float4*>(wp + OC);
          const float4 w2 = *reinterpret_cast<const float4*>(wp + 2 * OC);
          const float4 w3 = *reinterpret_cast<const float4*>(wp + 3 * OC);
          #pragma unroll
          for (int r = 0; r < RX; ++r) {
            const float4 iv = xv[r * SP + kx];
            FMA4(acc[r], iv.x, w0);
            FMA4(acc[r], iv.y, w1);
            FMA4(acc[r], iv.z, w2);
            FMA4(acc[r], iv.w, w3);
          }
        }
      }
    }
  }

  #pragma unroll
  for (int r = 0; r < RX; ++r) {
    acc[r].x = fmaxf(acc[r].x, 0.0f);
    acc[r].y = fmaxf(acc[r].y, 0.0f);
    acc[r].z = fmaxf(acc[r].z, 0.0f);
    acc[r].w = fmaxf(acc[r].w, 0.0f);
  }

  if constexpr (OUT_NCDHW) {
    // (B, OC, To, Ho, Wo); 4 oc planes, RX scalars each (small volume, ok)
    const size_t plane = (size_t)To * Ho * Wo;
    float* op = out + ((((size_t)b * OC + oc4 * 4) * To + t) * Ho + y) * Wo + xg;
    #pragma unroll
    for (int i = 0; i < 4; ++i) {
      #pragma unroll
      for (int r = 0; r < RX; ++r)
        op[(size_t)i * plane + r] = ((const float*)&acc[r])[i];
    }
  } else {
    float* op = out + (((size_t)(b * To + t) * Ho + y) * (Wo + 2) + xg + 1) * OC + oc4 * 4;
    #pragma unroll
    for (int r = 0; r < RX; ++r)
      *reinterpret_cast<float4*>(op + (size_t)r * OC) = acc[r];
    // write this row's x-halo zeros (ensures downstream reads are clean)
    const float4 z4 = make_float4(0.f, 0.f, 0.f, 0.f);
    if (xg == 0)        *reinterpret_cast<float4*>(op - OC) = z4;            // x=0
    if (xg + RX == Wo)  *reinterpret_cast<float4*>(op + (size_t)RX * OC) = z4; // x=Wo+1
  }
}

// ---------------- fp32 tiled GEMM: C = act(A * B^T + D + bias) ----------------
// A: (M,K) row-major, Bm: (N,K) row-major; D: optional (M,N), bias: optional (N).
// M,N multiples of 64; K multiple of 16.
__global__ __launch_bounds__(256) void gemm_nt(
    const float* __restrict__ A, const float* __restrict__ Bm,
    const float* __restrict__ D, const float* __restrict__ bias,
    float* __restrict__ C, int M, int N, int K, int relu)
{
  __shared__ float As[16][68];
  __shared__ float Bs[16][68];
  const int tid = threadIdx.x;
  const int kk = tid & 15, rr = tid >> 4;   // load mapping
  const int tx = tid & 15, ty = tid >> 4;   // compute mapping
  const int m0 = blockIdx.y * 64, n0 = blockIdx.x * 64;

  float acc[4][4];
  #pragma unroll
  for (int i = 0; i < 4; ++i)
    #pragma unroll
    for (int j = 0; j < 4; ++j) acc[i][j] = 0.f;

  for (int k0 = 0; k0 < K; k0 += 16) {
    #pragma unroll
    for (int p = 0; p < 4; ++p) {
      As[kk][rr + p * 16] = A[(size_t)(m0 + rr + p * 16) * K + (k0 + kk)];
      Bs[kk][rr + p * 16] = Bm[(size_t)(n0 + rr + p * 16) * K + (k0 + kk)];
    }
    __syncthreads();
    #pragma unroll
    for (int k = 0; k < 16; ++k) {
      const float4 av = *reinterpret_cast<const float4*>(&As[k][ty * 4]);
      const float4 bv = *reinterpret_cast<const float4*>(&Bs[k][tx * 4]);
      const float a_[4] = {av.x, av.y, av.z, av.w};
      const float b_[4] = {bv.x, bv.y, bv.z, bv.w};
      #pragma unroll
      for (int i = 0; i < 4; ++i)
        #pragma unroll
        for (int j = 0; j < 4; ++j)
          acc[i][j] = fmaf(a_[i], b_[j], acc[i][j]);
    }
    __syncthreads();
  }

  #pragma unroll
  for (int i = 0; i < 4; ++i) {
    const int m = m0 + ty * 4 + i;
    const int n = n0 + tx * 4;
    float4 v = make_float4(acc[i][0], acc[i][1], acc[i][2], acc[i][3]);
    if (D) {
      const float4 d4 = *reinterpret_cast<const float4*>(&D[(size_t)m * N + n]);
      v.x += d4.x; v.y += d4.y; v.z += d4.z; v.w += d4.w;
    }
    if (bias) {
      const float4 b4 = *reinterpret_cast<const float4*>(&bias[n]);
      v.x += b4.x; v.y += b4.y; v.z += b4.z; v.w += b4.w;
    }
    if (relu) {
      v.x = fmaxf(v.x, 0.f); v.y = fmaxf(v.y, 0.f);
      v.z = fmaxf(v.z, 0.f); v.w = fmaxf(v.w, 0.f);
    }
    *reinterpret_cast<float4*>(&C[(size_t)m * N + n]) = v;
  }
}

// ---------------- LSTM elementwise ----------------

__global__ __launch_bounds__(256) void lstm_mask(
    const float* __restrict__ h, const float* __restrict__ c,
    const float* __restrict__ done_l, float* __restrict__ hm, float* __restrict__ cm)
{
  int e = blockIdx.x * 256 + threadIdx.x;
  if (e >= 256 * 512) return;
  const float m = 1.f - done_l[e >> 9];
  hm[e] = h[e] * m;
  cm[e] = c[e] * m;
}

__global__ __launch_bounds__(256) void lstm_cell(
    const float* __restrict__ gates, const float* __restrict__ cm,
    float* __restrict__ hs_l, float* __restrict__ h_buf, float* __restrict__ c_buf,
    float* __restrict__ hT, float* __restrict__ cT)
{
  int e = blockIdx.x * 256 + threadIdx.x;
  if (e >= 256 * 512) return;
  const int b = e >> 9, u = e & 511;
  const float* gr = gates + (size_t)b * 2048;
  float i = gr[u], f = gr[512 + u], g = gr[1024 + u], o = gr[1536 + u];
  i = 1.f / (1.f + expf(-i));
  f = 1.f / (1.f + expf(-f));
  o = 1.f / (1.f + expf(-o));
  g = tanhf(g);
  const float cn = f * cm[e] + i * g;
  const float hn = o * tanhf(cn);
  hs_l[e] = hn; h_buf[e] = hn; c_buf[e] = cn;
  if (hT) { hT[e] = hn; cT[e] = cn; }
}

// logits (1280,5) = z (1280,512) @ fc2_w^T (512,5) + fc2_b
__global__ __launch_bounds__(256) void fc2_kernel(
    const float* __restrict__ z, const float* __restrict__ w,
    const float* __restrict__ b, float* __restrict__ out)
{
  int e = blockIdx.x * 256 + threadIdx.x;
  if (e >= 1280 * 5) return;
  const int n = e % 5, m = e / 5;
  const float* zr = z + (size_t)m * 512;
  const float* wr = w + (size_t)n * 512;
  float acc = b[n];
  for (int k = 0; k < 512; k += 4) {
    const float4 zv = *reinterpret_cast<const float4*>(zr + k);
    const float4 wv = *reinterpret_cast<const float4*>(wr + k);
    acc += zv.x * wv.x + zv.y * wv.y + zv.z * wv.z + zv.w * wv.w;
  }
  out[e] = acc;
}

// ---------------- host ----------------

extern "C" void kernel_launch(void* const* d_in, const int* in_sizes, int n_in,
                              void* d_out, int out_size, void* d_ws, size_t ws_size,
                              hipStream_t stream)
{
  const float* x    = (const float*)d_in[0];
  const float* done = (const float*)d_in[1];
  const float* h0   = (const float*)d_in[2];
  const float* c0   = (const float*)d_in[3];
  const float* w1a = (const float*)d_in[4];  const float* b1a = (const float*)d_in[5];
  const float* w1b = (const float*)d_in[6];  const float* b1b = (const float*)d_in[7];
  const float* w2a = (const float*)d_in[8];  const float* b2a = (const float*)d_in[9];
  const float* w2b = (const float*)d_in[10]; const float* b2b = (const float*)d_in[11];
  const float* w3a = (const float*)d_in[12]; const float* b3a = (const float*)d_in[13];
  const float* w3b = (const float*)d_in[14]; const float* b3b = (const float*)d_in[15];
  const float* W_ih = (const float*)d_in[16];
  const float* W_hh = (const float*)d_in[17];
  const float* b_ih = (const float*)d_in[18];
  const float* b_hh = (const float*)d_in[19];
  const float* fc1w = (const float*)d_in[20]; const float* fc1b = (const float*)d_in[21];
  const float* fc2w = (const float*)d_in[22]; const float* fc2b = (const float*)d_in[23];

  float* ws = (float*)d_ws;
  float* outp = (float*)d_out;
  (void)in_sizes; (void)n_in; (void)out_size;

  // ---------------- workspace layout (floats, all sizes 256-aligned) --------
  size_t off = 0;
  auto alloc = [&off](size_t n) { size_t r = off; off += (n + 255) & ~(size_t)255; return r; };
  // fixed region (lives the whole launch)
  const size_t o_w1a = alloc(18 * 4 * 32);
  const size_t o_w1b = alloc(18 * 32 * 32);
  const size_t o_w2a = alloc(18 * 32 * 64);
  const size_t o_w2b = alloc(18 * 64 * 64);
  const size_t o_w3a = alloc(18 * 64 * 128);
  const size_t o_w3b = alloc(18 * 128 * 128);
  const size_t o_bs  = alloc(2048);
  const size_t o_hid = alloc((size_t)1280 * 2048);  // conv3b out == LSTM input rows
  const size_t o_gx  = alloc((size_t)1280 * 2048);  // x-projection gates
  const size_t o_R   = off;                         // overlapped region start

  // LSTM-phase scratch (used only AFTER the conv chunks are done)
  size_t loff = o_R;
  auto lalloc = [&loff](size_t n) { size_t r = loff; loff += (n + 255) & ~(size_t)255; return r; };
  const size_t o_g  = lalloc((size_t)256 * 2048);
  const size_t o_hm = lalloc(256 * 512);
  const size_t o_cm = lalloc(256 * 512);
  const size_t o_h  = lalloc(256 * 512);
  const size_t o_c  = lalloc(256 * 512);
  const size_t o_hs = lalloc((size_t)1280 * 512);
  const size_t o_z  = lalloc((size_t)1280 * 512);

  // conv-phase chunk scratch (per batch-chunk, ping-pong), also starts at o_R
  const size_t XP_B = 34816;   // 16*16*34*4   (all multiples of 256)
  const size_t A_B  = 261120;  // 15*16*34*32  (max of conv1a/2a/3a outputs)
  const size_t B_B  = 64512;   // 14*8*18*32   (max of conv1b/2b outputs)
  const size_t PER_B = XP_B + A_B + B_B;      // 360448 floats per batch element

  const size_t ws_floats = ws_size / sizeof(float);
  const size_t avail = (ws_floats > o_R) ? (ws_floats - o_R) : 0;
  int CB = 256;
  while (CB > 1 && (size_t)CB * PER_B > avail) CB >>= 1;
  const int nchunks = 256 / CB;

  const size_t o_xp = o_R;
  const size_t o_A  = o_xp + (size_t)CB * XP_B;
  const size_t o_B  = o_A  + (size_t)CB * A_B;

  auto nblk = [](long long n) { return (unsigned)((n + 255) / 256); };

  // ---------------- prep ----------------
  wtrans_kernel<<<nblk(18 * 4 * 32), 256, 0, stream>>>(w1a, ws + o_w1a, 4, 32, 1.f / 255.f, 18 * 4 * 32);
  wtrans_kernel<<<nblk(18 * 32 * 32), 256, 0, stream>>>(w1b, ws + o_w1b, 32, 32, 1.f, 18 * 32 * 32);
  wtrans_kernel<<<nblk(18 * 32 * 64), 256, 0, stream>>>(w2a, ws + o_w2a, 32, 64, 1.f / 255.f, 18 * 32 * 64);
  wtrans_kernel<<<nblk(18 * 64 * 64), 256, 0, stream>>>(w2b, ws + o_w2b, 64, 64, 1.f, 18 * 64 * 64);
  wtrans_kernel<<<nblk(18 * 64 * 128), 256, 0, stream>>>(w3a, ws + o_w3a, 64, 128, 1.f / 255.f, 18 * 64 * 128);
  wtrans_kernel<<<nblk(18 * 128 * 128), 256, 0, stream>>>(w3b, ws + o_w3b, 128, 128, 1.f, 18 * 128 * 128);
  bsum_kernel<<<8, 256, 0, stream>>>(b_ih, b_hh, ws + o_bs);

  // ---------------- conv chain, chunked over batch ----------------
  // grid threads = CB * To * Ho * (Wo/RX) * (OC/4)
  for (int c = 0; c < nchunks; ++c) {
    const int b0 = c * CB;
    pad_x_kernel<<<nblk((long long)CB * 16 * 16 * 34), 256, 0, stream>>>(
        x + (size_t)b0 * 16 * 16 * 32 * 4, ws + o_xp, CB * 16 * 16 * 34);
    conv3d_relu<4, 32, 1, 4, false><<<nblk((long long)CB * 15 * 16 * 8 * 8), 256, 0, stream>>>(
        ws + o_xp, ws + o_w1a, b1a, ws + o_A, CB, 16, 16, 32, 15, 16, 32);
    conv3d_relu<32, 32, 2, 4, false><<<nblk((long long)CB * 14 * 8 * 4 * 8), 256, 0, stream>>>(
        ws + o_A, ws + o_w1b, b1b, ws + o_B, CB, 15, 16, 32, 14, 8, 16);
    conv3d_relu<32, 64, 1, 4, false><<<nblk((long long)CB * 13 * 8 * 4 * 16), 256, 0, stream>>>(
        ws + o_B, ws + o_w2a, b2a, ws + o_A, CB, 14, 8, 16, 13, 8, 16);
    conv3d_relu<64, 64, 2, 4, false><<<nblk((long long)CB * 12 * 4 * 2 * 16), 256, 0, stream>>>(
        ws + o_A, ws + o_w2b, b2b, ws + o_B, CB, 13, 8, 16, 12, 4, 8);
    conv3d_relu<64, 128, 1, 4, false><<<nblk((long long)CB * 11 * 4 * 2 * 32), 256, 0, stream>>>(
        ws + o_B, ws + o_w3a, b3a, ws + o_A, CB, 12, 4, 8, 11, 4, 8);
    conv3d_relu<128, 128, 2, 4, true><<<nblk((long long)CB * 10 * 2 * 1 * 32), 256, 0, stream>>>(
        ws + o_A, ws + o_w3b, b3b, ws + o_hid + (size_t)b0 * 10240, CB, 11, 4, 8, 10, 2, 4);
  }
  // ws+o_hid now holds "hidden" = (1280, 2048) row-major (faithful reshape free)

  // x-projection for all 5 steps: gatesx = hidden @ W_ih^T + (b_ih + b_hh)
  gemm_nt<<<dim3(2048 / 64, 1280 / 64), 256, 0, stream>>>(
      ws + o_hid, W_ih, nullptr, ws + o_bs, ws + o_gx, 1280, 2048, 2048, 0);

  // ---------------- recurrent steps ----------------
  for (int l = 0; l < 5; ++l) {
    const float* hsrc = (l == 0) ? h0 : ws + o_h;
    const float* csrc = (l == 0) ? c0 : ws + o_c;
    lstm_mask<<<512, 256, 0, stream>>>(hsrc, csrc, done + (size_t)l * 256,
                                       ws + o_hm, ws + o_cm);
    gemm_nt<<<dim3(2048 / 64, 256 / 64), 256, 0, stream>>>(
        ws + o_hm, W_hh, ws + o_gx + (size_t)l * 256 * 2048, nullptr,
        ws + o_g, 256, 2048, 512, 0);
    lstm_cell<<<512, 256, 0, stream>>>(
        ws + o_g, ws + o_cm, ws + o_hs + (size_t)l * 256 * 512, ws + o_h, ws + o_c,
        (l == 4) ? outp + 6400 : nullptr,
        (l == 4) ? outp + 6400 + 256 * 512 : nullptr);
  }

  // ---------------- heads ----------------
  gemm_nt<<<dim3(512 / 64, 1280 / 64), 256, 0, stream>>>(
      ws + o_hs, fc1w, nullptr, fc1b, ws + o_z, 1280, 512, 512, 1);
  fc2_kernel<<<nblk(1280 * 5), 256, 0, stream>>>(ws + o_z, fc2w, fc2b, outp);
}

// Round 6
// 4521.145 us; speedup vs baseline: 1.7494x; 1.0082x over previous
//
#include <hip/hip_runtime.h>
#include <cstddef>

// ---------------------------------------------------------------------------
// CNN(3 conv blocks) -> faithful reshape -> 5-step LSTM -> fc1(relu) -> fc2
// All fp32. Activations channels-last with x-only halo padding.
// Conv chain is chunked over batch (chunk size adapted to ws_size); conv3b
// writes NCDHW so its output IS the LSTM "hidden" matrix (1280x2048).
// conv1a (IC=4, the measured latency-bound hotspot) now has a dedicated
// LDS-staged kernel: input tile staged once per (b,t) block, y-padding
// materialized as zeros in LDS, compute reads are ds_read_b128 only.
// ---------------------------------------------------------------------------

// x chunk: (CB,16,16,32,4) -> xp: (CB,16,16,34,4) with x-halo zeros
__global__ __launch_bounds__(256) void pad_x_kernel(
    const float* __restrict__ x, float* __restrict__ xp, int total)
{
  int e = blockIdx.x * 256 + threadIdx.x;           // one float4 (ic) per thread
  if (e >= total) return;
  int xs = e % 34; int r = e / 34;
  float4 v = make_float4(0.f, 0.f, 0.f, 0.f);
  if (xs >= 1 && xs <= 32) {
    v = *reinterpret_cast<const float4*>(x + ((size_t)r * 32 + (xs - 1)) * 4);
  }
  *reinterpret_cast<float4*>(xp + (size_t)e * 4) = v;
}

// w: (OC,IC,2,3,3) -> wt: (k=kt*9+ky*3+kx, ic, oc), optional scale (folds /255)
__global__ __launch_bounds__(256) void wtrans_kernel(
    const float* __restrict__ w, float* __restrict__ wt,
    int IC, int OC, float scale, int total)
{
  int e = blockIdx.x * 256 + threadIdx.x;
  if (e >= total) return;
  int oc = e % OC; int t = e / OC; int ic = t % IC; int k = t / IC; // k in [0,18)
  int kt = k / 9; int r9 = k % 9; int ky = r9 / 3; int kx = r9 % 3;
  wt[e] = w[((((size_t)oc * IC + ic) * 2 + kt) * 3 + ky) * 3 + kx] * scale;
}

__global__ __launch_bounds__(256) void bsum_kernel(
    const float* __restrict__ a, const float* __restrict__ b, float* __restrict__ o)
{
  int e = blockIdx.x * 256 + threadIdx.x;
  if (e < 2048) o[e] = a[e] + b[e];
}

#define FMA4(A, S, W)                  \
  A.x = fmaf((S), (W).x, A.x);         \
  A.y = fmaf((S), (W).y, A.y);         \
  A.z = fmaf((S), (W).z, A.z);         \
  A.w = fmaf((S), (W).w, A.w)

// ---------------- conv1a: LDS-staged, IC=4, OC=32, SP=1 ----------------------
// One block per (b, t). Stage input planes t..t+1, y=-1..16 (zeros), x=0..33
// into LDS (19.6 KB), then each thread computes 8x * 8oc outputs from LDS.
// in : (B,16,16,34,4) channels-last, x-halo padded (xp)
// out: (B,15,16,34,32) channels-last, x-halo padded
// wt : (18, 4, 32), bias: (32). ReLU fused.
__global__ __launch_bounds__(256, 2) void conv1a_lds(
    const float* __restrict__ in, const float* __restrict__ wt,
    const float* __restrict__ bias, float* __restrict__ out, int B)
{
  __shared__ float4 sIn[2][18][34];
  const int b = blockIdx.x / 15;
  const int t = blockIdx.x % 15;
  const int tid = threadIdx.x;

  // ---- stage: 2*18*34 = 1224 float4s, coalesced, zeros at y=-1/16 ----
  const float4* in4 = reinterpret_cast<const float4*>(in);
  for (int e = tid; e < 1224; e += 256) {
    const int kt = e / 612, rem = e % 612;
    const int yy = rem / 34, xx = rem % 34;     // yy: 0..17 -> y = yy-1
    const int y = yy - 1;
    float4 v = make_float4(0.f, 0.f, 0.f, 0.f);
    if (y >= 0 && y < 16)
      v = in4[((size_t)(b * 16 + (t + kt)) * 16 + y) * 34 + xx];
    sIn[kt][yy][xx] = v;
  }
  __syncthreads();

  // ---- compute: thread = (y, xq, oc8): 16*4*4 = 256 ----
  const int oc8 = (tid & 3) * 8;        // oc base (2 quads)
  const int xq  = (tid >> 2) & 3;       // x group of 8
  const int y   = tid >> 4;             // 0..15
  const int xg  = xq * 8;

  float4 acc[8][2];
  const float4 bv0 = *reinterpret_cast<const float4*>(bias + oc8);
  const float4 bv1 = *reinterpret_cast<const float4*>(bias + oc8 + 4);
  #pragma unroll
  for (int r = 0; r < 8; ++r) { acc[r][0] = bv0; acc[r][1] = bv1; }

  #pragma unroll
  for (int kt = 0; kt < 2; ++kt) {
    #pragma unroll
    for (int ky = 0; ky < 3; ++ky) {
      const float4* __restrict__ row = &sIn[kt][y + ky][xg];
      float4 xv[10];
      #pragma unroll
      for (int p = 0; p < 10; ++p) xv[p] = row[p];
      #pragma unroll
      for (int kx = 0; kx < 3; ++kx) {
        const float* __restrict__ wp = wt + ((kt * 9 + ky * 3 + kx) * 4) * 32 + oc8;
        const float4 w00 = *reinterpret_cast<const float4*>(wp);            // ic0 q0
        const float4 w01 = *reinterpret_cast<const float4*>(wp + 4);        // ic0 q1
        const float4 w10 = *reinterpret_cast<const float4*>(wp + 32);
        const float4 w11 = *reinterpret_cast<const float4*>(wp + 36);
        const float4 w20 = *reinterpret_cast<const float4*>(wp + 64);
        const float4 w21 = *reinterpret_cast<const float4*>(wp + 68);
        const float4 w30 = *reinterpret_cast<const float4*>(wp + 96);
        const float4 w31 = *reinterpret_cast<const float4*>(wp + 100);
        #pragma unroll
        for (int r = 0; r < 8; ++r) {
          const float4 iv = xv[r + kx];
          FMA4(acc[r][0], iv.x, w00); FMA4(acc[r][1], iv.x, w01);
          FMA4(acc[r][0], iv.y, w10); FMA4(acc[r][1], iv.y, w11);
          FMA4(acc[r][0], iv.z, w20); FMA4(acc[r][1], iv.z, w21);
          FMA4(acc[r][0], iv.w, w30); FMA4(acc[r][1], iv.w, w31);
        }
      }
    }
  }

  // ---- relu + store (+ x-halo zeros) ----
  float* op = out + (((size_t)(b * 15 + t) * 16 + y) * 34 + xg + 1) * 32 + oc8;
  const float4 z4 = make_float4(0.f, 0.f, 0.f, 0.f);
  #pragma unroll
  for (int r = 0; r < 8; ++r) {
    #pragma unroll
    for (int q = 0; q < 2; ++q) {
      acc[r][q].x = fmaxf(acc[r][q].x, 0.f);
      acc[r][q].y = fmaxf(acc[r][q].y, 0.f);
      acc[r][q].z = fmaxf(acc[r][q].z, 0.f);
      acc[r][q].w = fmaxf(acc[r][q].w, 0.f);
      *reinterpret_cast<float4*>(op + (size_t)r * 32 + q * 4) = acc[r][q];
    }
  }
  if (xg == 0) {            // storage x = 0
    *reinterpret_cast<float4*>(op - 32) = z4;
    *reinterpret_cast<float4*>(op - 28) = z4;
  }
  if (xg == 24) {           // storage x = 33
    *reinterpret_cast<float4*>(op + (size_t)8 * 32) = z4;
    *reinterpret_cast<float4*>(op + (size_t)8 * 32 + 4) = z4;
  }
}

// ---------------- direct conv v2 (kd=2, 3x3 spatial, pad (0,1,1)) -------------
// input : (B, Ti, Hi, Wi+2, IC) channels-last, x-halo padded
// output: (B, To, Ho, Wo+2, OC) channels-last, x-halo padded (written here)
//         or NCDHW (B, OC, To, Ho, Wo) when OUT_NCDHW (no halo)
// weights: (18, IC, OC), bias: (OC). ReLU fused.
// Per thread: RX outputs along x times 4 consecutive oc (float4 accumulators).
template<int IC, int OC, int SP, int RX, bool OUT_NCDHW>
__global__ __launch_bounds__(256) void conv3d_relu(
    const float* __restrict__ in, const float* __restrict__ wt,
    const float* __restrict__ bias, float* __restrict__ out,
    int B, int Ti, int Hi, int Wi, int To, int Ho, int Wo)
{
  constexpr int NOC = OC / 4;             // oc-quads
  constexpr int NXW = (RX - 1) * SP + 3;  // input float4s per (kt,ky,ic4) window
  const int WT = Wo / RX;
  long long g = (long long)blockIdx.x * 256 + threadIdx.x;
  const int oc4 = (int)(g % NOC); g /= NOC;
  const int xt  = (int)(g % WT); g /= WT;
  const int y   = (int)(g % Ho); g /= Ho;
  const int t   = (int)(g % To);
  const int b   = (int)(g / To);
  if (b >= B) return;
  const int xg  = xt * RX;
  const int Wis = Wi + 2;

  float4 acc[RX];
  const float4 bv = *reinterpret_cast<const float4*>(bias + oc4 * 4);
  #pragma unroll
  for (int r = 0; r < RX; ++r) acc[r] = bv;

  #pragma unroll
  for (int kt = 0; kt < 2; ++kt) {
    const int it = t + kt;
    #pragma unroll
    for (int ky = 0; ky < 3; ++ky) {
      const int iy = y * SP + ky - 1;
      if (iy < 0 || iy >= Hi) continue;     // wave-uniform: free
      const float* __restrict__ inrow =
          in + (size_t)((b * Ti + it) * Hi + iy) * (size_t)(Wis * IC)
             + (size_t)(xg * SP) * IC;
      #pragma unroll 4
      for (int ic4 = 0; ic4 < IC / 4; ++ic4) {
        // input sliding window: x positions xg*SP + p, p in [0, NXW)
        float4 xv[NXW];
        #pragma unroll
        for (int p = 0; p < NXW; ++p)
          xv[p] = *reinterpret_cast<const float4*>(inrow + (size_t)p * IC + ic4 * 4);
        #pragma unroll
        for (int kx = 0; kx < 3; ++kx) {
          const float* __restrict__ wp =
              wt + ((size_t)((kt * 3 + ky) * 3 + kx) * IC + ic4 * 4) * OC + oc4 * 4;
          const float4 w0 = *reinterpret_cast<const float4*>(wp);
          const float4 w1 = *reinterpret_cast<const float4*>(wp + OC);
          const float4 w2 = *reinterpret_cast<const float4*>(wp + 2 * OC);
          const float4 w3 = *reinterpret_cast<const float4*>(wp + 3 * OC);
          #pragma unroll
          for (int r = 0; r < RX; ++r) {
            const float4 iv = xv[r * SP + kx];
            FMA4(acc[r], iv.x, w0);
            FMA4(acc[r], iv.y, w1);
            FMA4(acc[r], iv.z, w2);
            FMA4(acc[r], iv.w, w3);
          }
        }
      }
    }
  }

  #pragma unroll
  for (int r = 0; r < RX; ++r) {
    acc[r].x = fmaxf(acc[r].x, 0.0f);
    acc[r].y = fmaxf(acc[r].y, 0.0f);
    acc[r].z = fmaxf(acc[r].z, 0.0f);
    acc[r].w = fmaxf(acc[r].w, 0.0f);
  }

  if constexpr (OUT_NCDHW) {
    // (B, OC, To, Ho, Wo); 4 oc planes, RX scalars each (small volume, ok)
    const size_t plane = (size_t)To * Ho * Wo;
    float* op = out + ((((size_t)b * OC + oc4 * 4) * To + t) * Ho + y) * Wo + xg;
    #pragma unroll
    for (int i = 0; i < 4; ++i) {
      #pragma unroll
      for (int r = 0; r < RX; ++r)
        op[(size_t)i * plane + r] = ((const float*)&acc[r])[i];
    }
  } else {
    float* op = out + (((size_t)(b * To + t) * Ho + y) * (Wo + 2) + xg + 1) * OC + oc4 * 4;
    #pragma unroll
    for (int r = 0; r < RX; ++r)
      *reinterpret_cast<float4*>(op + (size_t)r * OC) = acc[r];
    // write this row's x-halo zeros (ensures downstream reads are clean)
    const float4 z4 = make_float4(0.f, 0.f, 0.f, 0.f);
    if (xg == 0)        *reinterpret_cast<float4*>(op - OC) = z4;            // x=0
    if (xg + RX == Wo)  *reinterpret_cast<float4*>(op + (size_t)RX * OC) = z4; // x=Wo+1
  }
}

// ---------------- fp32 tiled GEMM: C = act(A * B^T + D + bias) ----------------
// A: (M,K) row-major, Bm: (N,K) row-major; D: optional (M,N), bias: optional (N).
// M,N multiples of 64; K multiple of 16.
__global__ __launch_bounds__(256) void gemm_nt(
    const float* __restrict__ A, const float* __restrict__ Bm,
    const float* __restrict__ D, const float* __restrict__ bias,
    float* __restrict__ C, int M, int N, int K, int relu)
{
  __shared__ float As[16][68];
  __shared__ float Bs[16][68];
  const int tid = threadIdx.x;
  const int kk = tid & 15, rr = tid >> 4;   // load mapping
  const int tx = tid & 15, ty = tid >> 4;   // compute mapping
  const int m0 = blockIdx.y * 64, n0 = blockIdx.x * 64;

  float acc[4][4];
  #pragma unroll
  for (int i = 0; i < 4; ++i)
    #pragma unroll
    for (int j = 0; j < 4; ++j) acc[i][j] = 0.f;

  for (int k0 = 0; k0 < K; k0 += 16) {
    #pragma unroll
    for (int p = 0; p < 4; ++p) {
      As[kk][rr + p * 16] = A[(size_t)(m0 + rr + p * 16) * K + (k0 + kk)];
      Bs[kk][rr + p * 16] = Bm[(size_t)(n0 + rr + p * 16) * K + (k0 + kk)];
    }
    __syncthreads();
    #pragma unroll
    for (int k = 0; k < 16; ++k) {
      const float4 av = *reinterpret_cast<const float4*>(&As[k][ty * 4]);
      const float4 bv = *reinterpret_cast<const float4*>(&Bs[k][tx * 4]);
      const float a_[4] = {av.x, av.y, av.z, av.w};
      const float b_[4] = {bv.x, bv.y, bv.z, bv.w};
      #pragma unroll
      for (int i = 0; i < 4; ++i)
        #pragma unroll
        for (int j = 0; j < 4; ++j)
          acc[i][j] = fmaf(a_[i], b_[j], acc[i][j]);
    }
    __syncthreads();
  }

  #pragma unroll
  for (int i = 0; i < 4; ++i) {
    const int m = m0 + ty * 4 + i;
    const int n = n0 + tx * 4;
    float4 v = make_float4(acc[i][0], acc[i][1], acc[i][2], acc[i][3]);
    if (D) {
      const float4 d4 = *reinterpret_cast<const float4*>(&D[(size_t)m * N + n]);
      v.x += d4.x; v.y += d4.y; v.z += d4.z; v.w += d4.w;
    }
    if (bias) {
      const float4 b4 = *reinterpret_cast<const float4*>(&bias[n]);
      v.x += b4.x; v.y += b4.y; v.z += b4.z; v.w += b4.w;
    }
    if (relu) {
      v.x = fmaxf(v.x, 0.f); v.y = fmaxf(v.y, 0.f);
      v.z = fmaxf(v.z, 0.f); v.w = fmaxf(v.w, 0.f);
    }
    *reinterpret_cast<float4*>(&C[(size_t)m * N + n]) = v;
  }
}

// ---------------- LSTM elementwise ----------------

__global__ __launch_bounds__(256) void lstm_mask(
    const float* __restrict__ h, const float* __restrict__ c,
    const float* __restrict__ done_l, float* __restrict__ hm, float* __restrict__ cm)
{
  int e = blockIdx.x * 256 + threadIdx.x;
  if (e >= 256 * 512) return;
  const float m = 1.f - done_l[e >> 9];
  hm[e] = h[e] * m;
  cm[e] = c[e] * m;
}

__global__ __launch_bounds__(256) void lstm_cell(
    const float* __restrict__ gates, const float* __restrict__ cm,
    float* __restrict__ hs_l, float* __restrict__ h_buf, float* __restrict__ c_buf,
    float* __restrict__ hT, float* __restrict__ cT)
{
  int e = blockIdx.x * 256 + threadIdx.x;
  if (e >= 256 * 512) return;
  const int b = e >> 9, u = e & 511;
  const float* gr = gates + (size_t)b * 2048;
  float i = gr[u], f = gr[512 + u], g = gr[1024 + u], o = gr[1536 + u];
  i = 1.f / (1.f + expf(-i));
  f = 1.f / (1.f + expf(-f));
  o = 1.f / (1.f + expf(-o));
  g = tanhf(g);
  const float cn = f * cm[e] + i * g;
  const float hn = o * tanhf(cn);
  hs_l[e] = hn; h_buf[e] = hn; c_buf[e] = cn;
  if (hT) { hT[e] = hn; cT[e] = cn; }
}

// logits (1280,5) = z (1280,512) @ fc2_w^T (512,5) + fc2_b
__global__ __launch_bounds__(256) void fc2_kernel(
    const float* __restrict__ z, const float* __restrict__ w,
    const float* __restrict__ b, float* __restrict__ out)
{
  int e = blockIdx.x * 256 + threadIdx.x;
  if (e >= 1280 * 5) return;
  const int n = e % 5, m = e / 5;
  const float* zr = z + (size_t)m * 512;
  const float* wr = w + (size_t)n * 512;
  float acc = b[n];
  for (int k = 0; k < 512; k += 4) {
    const float4 zv = *reinterpret_cast<const float4*>(zr + k);
    const float4 wv = *reinterpret_cast<const float4*>(wr + k);
    acc += zv.x * wv.x + zv.y * wv.y + zv.z * wv.z + zv.w * wv.w;
  }
  out[e] = acc;
}

// ---------------- host ----------------

extern "C" void kernel_launch(void* const* d_in, const int* in_sizes, int n_in,
                              void* d_out, int out_size, void* d_ws, size_t ws_size,
                              hipStream_t stream)
{
  const float* x    = (const float*)d_in[0];
  const float* done = (const float*)d_in[1];
  const float* h0   = (const float*)d_in[2];
  const float* c0   = (const float*)d_in[3];
  const float* w1a = (const float*)d_in[4];  const float* b1a = (const float*)d_in[5];
  const float* w1b = (const float*)d_in[6];  const float* b1b = (const float*)d_in[7];
  const float* w2a = (const float*)d_in[8];  const float* b2a = (const float*)d_in[9];
  const float* w2b = (const float*)d_in[10]; const float* b2b = (const float*)d_in[11];
  const float* w3a = (const float*)d_in[12]; const float* b3a = (const float*)d_in[13];
  const float* w3b = (const float*)d_in[14]; const float* b3b = (const float*)d_in[15];
  const float* W_ih = (const float*)d_in[16];
  const float* W_hh = (const float*)d_in[17];
  const float* b_ih = (const float*)d_in[18];
  const float* b_hh = (const float*)d_in[19];
  const float* fc1w = (const float*)d_in[20]; const float* fc1b = (const float*)d_in[21];
  const float* fc2w = (const float*)d_in[22]; const float* fc2b = (const float*)d_in[23];

  float* ws = (float*)d_ws;
  float* outp = (float*)d_out;
  (void)in_sizes; (void)n_in; (void)out_size;

  // ---------------- workspace layout (floats, all sizes 256-aligned) --------
  size_t off = 0;
  auto alloc = [&off](size_t n) { size_t r = off; off += (n + 255) & ~(size_t)255; return r; };
  // fixed region (lives the whole launch)
  const size_t o_w1a = alloc(18 * 4 * 32);
  const size_t o_w1b = alloc(18 * 32 * 32);
  const size_t o_w2a = alloc(18 * 32 * 64);
  const size_t o_w2b = alloc(18 * 64 * 64);
  const size_t o_w3a = alloc(18 * 64 * 128);
  const size_t o_w3b = alloc(18 * 128 * 128);
  const size_t o_bs  = alloc(2048);
  const size_t o_hid = alloc((size_t)1280 * 2048);  // conv3b out == LSTM input rows
  const size_t o_gx  = alloc((size_t)1280 * 2048);  // x-projection gates
  const size_t o_R   = off;                         // overlapped region start

  // LSTM-phase scratch (used only AFTER the conv chunks are done)
  size_t loff = o_R;
  auto lalloc = [&loff](size_t n) { size_t r = loff; loff += (n + 255) & ~(size_t)255; return r; };
  const size_t o_g  = lalloc((size_t)256 * 2048);
  const size_t o_hm = lalloc(256 * 512);
  const size_t o_cm = lalloc(256 * 512);
  const size_t o_h  = lalloc(256 * 512);
  const size_t o_c  = lalloc(256 * 512);
  const size_t o_hs = lalloc((size_t)1280 * 512);
  const size_t o_z  = lalloc((size_t)1280 * 512);

  // conv-phase chunk scratch (per batch-chunk, ping-pong), also starts at o_R
  const size_t XP_B = 34816;   // 16*16*34*4   (all multiples of 256)
  const size_t A_B  = 261120;  // 15*16*34*32  (max of conv1a/2a/3a outputs)
  const size_t B_B  = 64512;   // 14*8*18*32   (max of conv1b/2b outputs)
  const size_t PER_B = XP_B + A_B + B_B;      // 360448 floats per batch element

  const size_t ws_floats = ws_size / sizeof(float);
  const size_t avail = (ws_floats > o_R) ? (ws_floats - o_R) : 0;
  int CB = 256;
  while (CB > 1 && (size_t)CB * PER_B > avail) CB >>= 1;
  const int nchunks = 256 / CB;

  const size_t o_xp = o_R;
  const size_t o_A  = o_xp + (size_t)CB * XP_B;
  const size_t o_B  = o_A  + (size_t)CB * A_B;

  auto nblk = [](long long n) { return (unsigned)((n + 255) / 256); };

  // ---------------- prep ----------------
  wtrans_kernel<<<nblk(18 * 4 * 32), 256, 0, stream>>>(w1a, ws + o_w1a, 4, 32, 1.f / 255.f, 18 * 4 * 32);
  wtrans_kernel<<<nblk(18 * 32 * 32), 256, 0, stream>>>(w1b, ws + o_w1b, 32, 32, 1.f, 18 * 32 * 32);
  wtrans_kernel<<<nblk(18 * 32 * 64), 256, 0, stream>>>(w2a, ws + o_w2a, 32, 64, 1.f / 255.f, 18 * 32 * 64);
  wtrans_kernel<<<nblk(18 * 64 * 64), 256, 0, stream>>>(w2b, ws + o_w2b, 64, 64, 1.f, 18 * 64 * 64);
  wtrans_kernel<<<nblk(18 * 64 * 128), 256, 0, stream>>>(w3a, ws + o_w3a, 64, 128, 1.f / 255.f, 18 * 64 * 128);
  wtrans_kernel<<<nblk(18 * 128 * 128), 256, 0, stream>>>(w3b, ws + o_w3b, 128, 128, 1.f, 18 * 128 * 128);
  bsum_kernel<<<8, 256, 0, stream>>>(b_ih, b_hh, ws + o_bs);

  // ---------------- conv chain, chunked over batch ----------------
  for (int c = 0; c < nchunks; ++c) {
    const int b0 = c * CB;
    pad_x_kernel<<<nblk((long long)CB * 16 * 16 * 34), 256, 0, stream>>>(
        x + (size_t)b0 * 16 * 16 * 32 * 4, ws + o_xp, CB * 16 * 16 * 34);
    conv1a_lds<<<CB * 15, 256, 0, stream>>>(
        ws + o_xp, ws + o_w1a, b1a, ws + o_A, CB);
    conv3d_relu<32, 32, 2, 4, false><<<nblk((long long)CB * 14 * 8 * 4 * 8), 256, 0, stream>>>(
        ws + o_A, ws + o_w1b, b1b, ws + o_B, CB, 15, 16, 32, 14, 8, 16);
    conv3d_relu<32, 64, 1, 4, false><<<nblk((long long)CB * 13 * 8 * 4 * 16), 256, 0, stream>>>(
        ws + o_B, ws + o_w2a, b2a, ws + o_A, CB, 14, 8, 16, 13, 8, 16);
    conv3d_relu<64, 64, 2, 4, false><<<nblk((long long)CB * 12 * 4 * 2 * 16), 256, 0, stream>>>(
        ws + o_A, ws + o_w2b, b2b, ws + o_B, CB, 13, 8, 16, 12, 4, 8);
    conv3d_relu<64, 128, 1, 4, false><<<nblk((long long)CB * 11 * 4 * 2 * 32), 256, 0, stream>>>(
        ws + o_B, ws + o_w3a, b3a, ws + o_A, CB, 12, 4, 8, 11, 4, 8);
    conv3d_relu<128, 128, 2, 4, true><<<nblk((long long)CB * 10 * 2 * 1 * 32), 256, 0, stream>>>(
        ws + o_A, ws + o_w3b, b3b, ws + o_hid + (size_t)b0 * 10240, CB, 11, 4, 8, 10, 2, 4);
  }
  // ws+o_hid now holds "hidden" = (1280, 2048) row-major (faithful reshape free)

  // x-projection for all 5 steps: gatesx = hidden @ W_ih^T + (b_ih + b_hh)
  gemm_nt<<<dim3(2048 / 64, 1280 / 64), 256, 0, stream>>>(
      ws + o_hid, W_ih, nullptr, ws + o_bs, ws + o_gx, 1280, 2048, 2048, 0);

  // ---------------- recurrent steps ----------------
  for (int l = 0; l < 5; ++l) {
    const float* hsrc = (l == 0) ? h0 : ws + o_h;
    const float* csrc = (l == 0) ? c0 : ws + o_c;
    lstm_mask<<<512, 256, 0, stream>>>(hsrc, csrc, done + (size_t)l * 256,
                                       ws + o_hm, ws + o_cm);
    gemm_nt<<<dim3(2048 / 64, 256 / 64), 256, 0, stream>>>(
        ws + o_hm, W_hh, ws + o_gx + (size_t)l * 256 * 2048, nullptr,
        ws + o_g, 256, 2048, 512, 0);
    lstm_cell<<<512, 256, 0, stream>>>(
        ws + o_g, ws + o_cm, ws + o_hs + (size_t)l * 256 * 512, ws + o_h, ws + o_c,
        (l == 4) ? outp + 6400 : nullptr,
        (l == 4) ? outp + 6400 + 256 * 512 : nullptr);
  }

  // ---------------- heads ----------------
  gemm_nt<<<dim3(512 / 64, 1280 / 64), 256, 0, stream>>>(
      ws + o_hs, fc1w, nullptr, fc1b, ws + o_z, 1280, 512, 512, 1);
  fc2_kernel<<<nblk(1280 * 5), 256, 0, stream>>>(ws + o_z, fc2w, fc2b, outp);
}

// Round 7
// 2752.496 us; speedup vs baseline: 2.8735x; 1.6426x over previous
//
#include <hip/hip_runtime.h>
#include <cstddef>

// ---------------------------------------------------------------------------
// CNN(3 conv blocks) -> faithful reshape -> 5-step LSTM -> fc1(relu) -> fc2
// All fp32. Activations channels-last with x-only halo padding.
// Conv chain chunked over batch (CB from ws_size); conv3b writes NCDHW so its
// output IS the LSTM "hidden" matrix (1280x2048).
// conv3d_relu v3: ic4-outer loop with the 18x4xOC weight slice staged in LDS
// per chunk (weights were the measured L2-latency stall: conv2a 438us,
// VALUBusy 25%, VGPR 132). Inputs stay in L1 (block-broadcast friendly).
// lstm_mask fused into the h-GEMM A-load and lstm_cell.
// ---------------------------------------------------------------------------

// x chunk: (CB,16,16,32,4) -> xp: (CB,16,16,34,4) with x-halo zeros
__global__ __launch_bounds__(256) void pad_x_kernel(
    const float* __restrict__ x, float* __restrict__ xp, int total)
{
  int e = blockIdx.x * 256 + threadIdx.x;           // one float4 (ic) per thread
  if (e >= total) return;
  int xs = e % 34; int r = e / 34;
  float4 v = make_float4(0.f, 0.f, 0.f, 0.f);
  if (xs >= 1 && xs <= 32) {
    v = *reinterpret_cast<const float4*>(x + ((size_t)r * 32 + (xs - 1)) * 4);
  }
  *reinterpret_cast<float4*>(xp + (size_t)e * 4) = v;
}

// w: (OC,IC,2,3,3) -> wt: (k=kt*9+ky*3+kx, ic, oc), optional scale (folds /255)
__global__ __launch_bounds__(256) void wtrans_kernel(
    const float* __restrict__ w, float* __restrict__ wt,
    int IC, int OC, float scale, int total)
{
  int e = blockIdx.x * 256 + threadIdx.x;
  if (e >= total) return;
  int oc = e % OC; int t = e / OC; int ic = t % IC; int k = t / IC; // k in [0,18)
  int kt = k / 9; int r9 = k % 9; int ky = r9 / 3; int kx = r9 % 3;
  wt[e] = w[((((size_t)oc * IC + ic) * 2 + kt) * 3 + ky) * 3 + kx] * scale;
}

__global__ __launch_bounds__(256) void bsum_kernel(
    const float* __restrict__ a, const float* __restrict__ b, float* __restrict__ o)
{
  int e = blockIdx.x * 256 + threadIdx.x;
  if (e < 2048) o[e] = a[e] + b[e];
}

#define FMA4(A, S, W)                  \
  A.x = fmaf((S), (W).x, A.x);         \
  A.y = fmaf((S), (W).y, A.y);         \
  A.z = fmaf((S), (W).z, A.z);         \
  A.w = fmaf((S), (W).w, A.w)

// ---------------- conv1a: LDS-staged, IC=4, OC=32, SP=1 ----------------------
__global__ __launch_bounds__(256, 2) void conv1a_lds(
    const float* __restrict__ in, const float* __restrict__ wt,
    const float* __restrict__ bias, float* __restrict__ out, int B)
{
  __shared__ float4 sIn[2][18][34];
  const int b = blockIdx.x / 15;
  const int t = blockIdx.x % 15;
  const int tid = threadIdx.x;

  const float4* in4 = reinterpret_cast<const float4*>(in);
  for (int e = tid; e < 1224; e += 256) {
    const int kt = e / 612, rem = e % 612;
    const int yy = rem / 34, xx = rem % 34;     // yy: 0..17 -> y = yy-1
    const int y = yy - 1;
    float4 v = make_float4(0.f, 0.f, 0.f, 0.f);
    if (y >= 0 && y < 16)
      v = in4[((size_t)(b * 16 + (t + kt)) * 16 + y) * 34 + xx];
    sIn[kt][yy][xx] = v;
  }
  __syncthreads();

  const int oc8 = (tid & 3) * 8;
  const int xq  = (tid >> 2) & 3;
  const int y   = tid >> 4;
  const int xg  = xq * 8;

  float4 acc[8][2];
  const float4 bv0 = *reinterpret_cast<const float4*>(bias + oc8);
  const float4 bv1 = *reinterpret_cast<const float4*>(bias + oc8 + 4);
  #pragma unroll
  for (int r = 0; r < 8; ++r) { acc[r][0] = bv0; acc[r][1] = bv1; }

  #pragma unroll
  for (int kt = 0; kt < 2; ++kt) {
    #pragma unroll
    for (int ky = 0; ky < 3; ++ky) {
      const float4* __restrict__ row = &sIn[kt][y + ky][xg];
      float4 xv[10];
      #pragma unroll
      for (int p = 0; p < 10; ++p) xv[p] = row[p];
      #pragma unroll
      for (int kx = 0; kx < 3; ++kx) {
        const float* __restrict__ wp = wt + ((kt * 9 + ky * 3 + kx) * 4) * 32 + oc8;
        const float4 w00 = *reinterpret_cast<const float4*>(wp);
        const float4 w01 = *reinterpret_cast<const float4*>(wp + 4);
        const float4 w10 = *reinterpret_cast<const float4*>(wp + 32);
        const float4 w11 = *reinterpret_cast<const float4*>(wp + 36);
        const float4 w20 = *reinterpret_cast<const float4*>(wp + 64);
        const float4 w21 = *reinterpret_cast<const float4*>(wp + 68);
        const float4 w30 = *reinterpret_cast<const float4*>(wp + 96);
        const float4 w31 = *reinterpret_cast<const float4*>(wp + 100);
        #pragma unroll
        for (int r = 0; r < 8; ++r) {
          const float4 iv = xv[r + kx];
          FMA4(acc[r][0], iv.x, w00); FMA4(acc[r][1], iv.x, w01);
          FMA4(acc[r][0], iv.y, w10); FMA4(acc[r][1], iv.y, w11);
          FMA4(acc[r][0], iv.z, w20); FMA4(acc[r][1], iv.z, w21);
          FMA4(acc[r][0], iv.w, w30); FMA4(acc[r][1], iv.w, w31);
        }
      }
    }
  }

  float* op = out + (((size_t)(b * 15 + t) * 16 + y) * 34 + xg + 1) * 32 + oc8;
  const float4 z4 = make_float4(0.f, 0.f, 0.f, 0.f);
  #pragma unroll
  for (int r = 0; r < 8; ++r) {
    #pragma unroll
    for (int q = 0; q < 2; ++q) {
      acc[r][q].x = fmaxf(acc[r][q].x, 0.f);
      acc[r][q].y = fmaxf(acc[r][q].y, 0.f);
      acc[r][q].z = fmaxf(acc[r][q].z, 0.f);
      acc[r][q].w = fmaxf(acc[r][q].w, 0.f);
      *reinterpret_cast<float4*>(op + (size_t)r * 32 + q * 4) = acc[r][q];
    }
  }
  if (xg == 0) {
    *reinterpret_cast<float4*>(op - 32) = z4;
    *reinterpret_cast<float4*>(op - 28) = z4;
  }
  if (xg == 24) {
    *reinterpret_cast<float4*>(op + (size_t)8 * 32) = z4;
    *reinterpret_cast<float4*>(op + (size_t)8 * 32 + 4) = z4;
  }
}

// ---------------- direct conv v3: ic4-outer, weights staged in LDS -----------
// input : (B, Ti, Hi, Wi+2, IC) channels-last, x-halo padded
// output: (B, To, Ho, Wo+2, OC) channels-last, x-halo padded, or NCDHW
// weights: (18, IC, OC), bias: (OC). ReLU fused.
// Per thread: RX outputs along x times 4 consecutive oc (float4 accumulators).
template<int IC, int OC, int SP, int RX, bool OUT_NCDHW>
__global__ __launch_bounds__(256) void conv3d_relu(
    const float* __restrict__ in, const float* __restrict__ wt,
    const float* __restrict__ bias, float* __restrict__ out,
    int B, int Ti, int Hi, int Wi, int To, int Ho, int Wo)
{
  constexpr int NOC = OC / 4;             // oc-quads
  constexpr int NXW = (RX - 1) * SP + 3;  // input float4s per (kt,ky) window
  __shared__ float sW[18 * 4 * OC];       // current ic4 chunk of weights
  const int tid = threadIdx.x;
  const int WT = Wo / RX;
  long long g = (long long)blockIdx.x * 256 + tid;
  const int oc4 = (int)(g % NOC); g /= NOC;
  const int xt  = (int)(g % WT); g /= WT;
  const int y   = (int)(g % Ho); g /= Ho;
  const int t   = (int)(g % To);
  int b         = (int)(g / To);
  const bool active = (b < B);            // padded threads still hit barriers
  if (!active) b = 0;
  const int xg  = xt * RX;
  const int Wis = Wi + 2;

  float4 acc[RX];
  const float4 bv = *reinterpret_cast<const float4*>(bias + oc4 * 4);
  #pragma unroll
  for (int r = 0; r < RX; ++r) acc[r] = bv;

  for (int ic4 = 0; ic4 < IC / 4; ++ic4) {
    __syncthreads();   // previous chunk fully consumed
    // stage wt[k=0..18, ic4*4..+4, :] -> sW (linear copy, 18*OC float4s)
    for (int e = tid; e < 18 * OC; e += 256) {
      const int k = e / OC, j4 = e % OC;
      reinterpret_cast<float4*>(sW)[(size_t)k * OC + j4] =
          reinterpret_cast<const float4*>(wt)[((size_t)k * IC + ic4 * 4) * (OC / 4) + j4];
    }
    __syncthreads();

    #pragma unroll
    for (int kt = 0; kt < 2; ++kt) {
      const int it = t + kt;
      #pragma unroll
      for (int ky = 0; ky < 3; ++ky) {
        const int iy = y * SP + ky - 1;
        if (iy < 0 || iy >= Hi) continue;     // no barriers inside: safe
        const float* __restrict__ inrow =
            in + (size_t)((b * Ti + it) * Hi + iy) * (size_t)(Wis * IC)
               + (size_t)(xg * SP) * IC + ic4 * 4;
        float4 xv[NXW];
        #pragma unroll
        for (int p = 0; p < NXW; ++p)
          xv[p] = *reinterpret_cast<const float4*>(inrow + (size_t)p * IC);
        #pragma unroll
        for (int kx = 0; kx < 3; ++kx) {
          const float* __restrict__ wp =
              sW + (size_t)(((kt * 3 + ky) * 3 + kx) * 4) * OC + oc4 * 4;
          const float4 w0 = *reinterpret_cast<const float4*>(wp);
          const float4 w1 = *reinterpret_cast<const float4*>(wp + OC);
          const float4 w2 = *reinterpret_cast<const float4*>(wp + 2 * OC);
          const float4 w3 = *reinterpret_cast<const float4*>(wp + 3 * OC);
          #pragma unroll
          for (int r = 0; r < RX; ++r) {
            const float4 iv = xv[r * SP + kx];
            FMA4(acc[r], iv.x, w0);
            FMA4(acc[r], iv.y, w1);
            FMA4(acc[r], iv.z, w2);
            FMA4(acc[r], iv.w, w3);
          }
        }
      }
    }
  }

  if (!active) return;

  #pragma unroll
  for (int r = 0; r < RX; ++r) {
    acc[r].x = fmaxf(acc[r].x, 0.0f);
    acc[r].y = fmaxf(acc[r].y, 0.0f);
    acc[r].z = fmaxf(acc[r].z, 0.0f);
    acc[r].w = fmaxf(acc[r].w, 0.0f);
  }

  if constexpr (OUT_NCDHW) {
    const size_t plane = (size_t)To * Ho * Wo;
    float* op = out + ((((size_t)b * OC + oc4 * 4) * To + t) * Ho + y) * Wo + xg;
    #pragma unroll
    for (int i = 0; i < 4; ++i) {
      #pragma unroll
      for (int r = 0; r < RX; ++r)
        op[(size_t)i * plane + r] = ((const float*)&acc[r])[i];
    }
  } else {
    float* op = out + (((size_t)(b * To + t) * Ho + y) * (Wo + 2) + xg + 1) * OC + oc4 * 4;
    #pragma unroll
    for (int r = 0; r < RX; ++r)
      *reinterpret_cast<float4*>(op + (size_t)r * OC) = acc[r];
    const float4 z4 = make_float4(0.f, 0.f, 0.f, 0.f);
    if (xg == 0)        *reinterpret_cast<float4*>(op - OC) = z4;              // x=0
    if (xg + RX == Wo)  *reinterpret_cast<float4*>(op + (size_t)RX * OC) = z4; // x=Wo+1
  }
}

// ---------------- fp32 tiled GEMM: C = act(diag(1-Amask)*A * B^T + D + bias) --
// A: (M,K) row-major, Bm: (N,K) row-major; D: optional (M,N), bias: optional (N).
// Amask: optional (M) — A row m scaled by (1 - Amask[m]) on load (LSTM done mask).
// M,N multiples of 64; K multiple of 16.
__global__ __launch_bounds__(256) void gemm_nt(
    const float* __restrict__ A, const float* __restrict__ Bm,
    const float* __restrict__ D, const float* __restrict__ bias,
    float* __restrict__ C, int M, int N, int K, int relu,
    const float* __restrict__ Amask)
{
  __shared__ float As[16][68];
  __shared__ float Bs[16][68];
  const int tid = threadIdx.x;
  const int kk = tid & 15, rr = tid >> 4;   // load mapping
  const int tx = tid & 15, ty = tid >> 4;   // compute mapping
  const int m0 = blockIdx.y * 64, n0 = blockIdx.x * 64;

  float acc[4][4];
  #pragma unroll
  for (int i = 0; i < 4; ++i)
    #pragma unroll
    for (int j = 0; j < 4; ++j) acc[i][j] = 0.f;

  for (int k0 = 0; k0 < K; k0 += 16) {
    #pragma unroll
    for (int p = 0; p < 4; ++p) {
      const int m = m0 + rr + p * 16;
      const float s = Amask ? (1.f - Amask[m]) : 1.f;
      As[kk][rr + p * 16] = A[(size_t)m * K + (k0 + kk)] * s;
      Bs[kk][rr + p * 16] = Bm[(size_t)(n0 + rr + p * 16) * K + (k0 + kk)];
    }
    __syncthreads();
    #pragma unroll
    for (int k = 0; k < 16; ++k) {
      const float4 av = *reinterpret_cast<const float4*>(&As[k][ty * 4]);
      const float4 bv = *reinterpret_cast<const float4*>(&Bs[k][tx * 4]);
      const float a_[4] = {av.x, av.y, av.z, av.w};
      const float b_[4] = {bv.x, bv.y, bv.z, bv.w};
      #pragma unroll
      for (int i = 0; i < 4; ++i)
        #pragma unroll
        for (int j = 0; j < 4; ++j)
          acc[i][j] = fmaf(a_[i], b_[j], acc[i][j]);
    }
    __syncthreads();
  }

  #pragma unroll
  for (int i = 0; i < 4; ++i) {
    const int m = m0 + ty * 4 + i;
    const int n = n0 + tx * 4;
    float4 v = make_float4(acc[i][0], acc[i][1], acc[i][2], acc[i][3]);
    if (D) {
      const float4 d4 = *reinterpret_cast<const float4*>(&D[(size_t)m * N + n]);
      v.x += d4.x; v.y += d4.y; v.z += d4.z; v.w += d4.w;
    }
    if (bias) {
      const float4 b4 = *reinterpret_cast<const float4*>(&bias[n]);
      v.x += b4.x; v.y += b4.y; v.z += b4.z; v.w += b4.w;
    }
    if (relu) {
      v.x = fmaxf(v.x, 0.f); v.y = fmaxf(v.y, 0.f);
      v.z = fmaxf(v.z, 0.f); v.w = fmaxf(v.w, 0.f);
    }
    *reinterpret_cast<float4*>(&C[(size_t)m * N + n]) = v;
  }
}

// ---------------- LSTM cell (mask fused: cm = c_prev * (1-done)) -------------
__global__ __launch_bounds__(256) void lstm_cell(
    const float* __restrict__ gates, const float* __restrict__ c_prev,
    const float* __restrict__ done_l,
    float* __restrict__ hs_l, float* __restrict__ h_buf, float* __restrict__ c_buf,
    float* __restrict__ hT, float* __restrict__ cT)
{
  int e = blockIdx.x * 256 + threadIdx.x;
  if (e >= 256 * 512) return;
  const int b = e >> 9, u = e & 511;
  const float* gr = gates + (size_t)b * 2048;
  float i = gr[u], f = gr[512 + u], g = gr[1024 + u], o = gr[1536 + u];
  i = 1.f / (1.f + expf(-i));
  f = 1.f / (1.f + expf(-f));
  o = 1.f / (1.f + expf(-o));
  g = tanhf(g);
  const float cm = c_prev[e] * (1.f - done_l[b]);
  const float cn = f * cm + i * g;
  const float hn = o * tanhf(cn);
  hs_l[e] = hn; h_buf[e] = hn; c_buf[e] = cn;
  if (hT) { hT[e] = hn; cT[e] = cn; }
}

// logits (1280,5) = z (1280,512) @ fc2_w^T (512,5) + fc2_b
__global__ __launch_bounds__(256) void fc2_kernel(
    const float* __restrict__ z, const float* __restrict__ w,
    const float* __restrict__ b, float* __restrict__ out)
{
  int e = blockIdx.x * 256 + threadIdx.x;
  if (e >= 1280 * 5) return;
  const int n = e % 5, m = e / 5;
  const float* zr = z + (size_t)m * 512;
  const float* wr = w + (size_t)n * 512;
  float acc = b[n];
  for (int k = 0; k < 512; k += 4) {
    const float4 zv = *reinterpret_cast<const float4*>(zr + k);
    const float4 wv = *reinterpret_cast<const float4*>(wr + k);
    acc += zv.x * wv.x + zv.y * wv.y + zv.z * wv.z + zv.w * wv.w;
  }
  out[e] = acc;
}

// ---------------- host ----------------

extern "C" void kernel_launch(void* const* d_in, const int* in_sizes, int n_in,
                              void* d_out, int out_size, void* d_ws, size_t ws_size,
                              hipStream_t stream)
{
  const float* x    = (const float*)d_in[0];
  const float* done = (const float*)d_in[1];
  const float* h0   = (const float*)d_in[2];
  const float* c0   = (const float*)d_in[3];
  const float* w1a = (const float*)d_in[4];  const float* b1a = (const float*)d_in[5];
  const float* w1b = (const float*)d_in[6];  const float* b1b = (const float*)d_in[7];
  const float* w2a = (const float*)d_in[8];  const float* b2a = (const float*)d_in[9];
  const float* w2b = (const float*)d_in[10]; const float* b2b = (const float*)d_in[11];
  const float* w3a = (const float*)d_in[12]; const float* b3a = (const float*)d_in[13];
  const float* w3b = (const float*)d_in[14]; const float* b3b = (const float*)d_in[15];
  const float* W_ih = (const float*)d_in[16];
  const float* W_hh = (const float*)d_in[17];
  const float* b_ih = (const float*)d_in[18];
  const float* b_hh = (const float*)d_in[19];
  const float* fc1w = (const float*)d_in[20]; const float* fc1b = (const float*)d_in[21];
  const float* fc2w = (const float*)d_in[22]; const float* fc2b = (const float*)d_in[23];

  float* ws = (float*)d_ws;
  float* outp = (float*)d_out;
  (void)in_sizes; (void)n_in; (void)out_size;

  // ---------------- workspace layout (floats, all sizes 256-aligned) --------
  size_t off = 0;
  auto alloc = [&off](size_t n) { size_t r = off; off += (n + 255) & ~(size_t)255; return r; };
  const size_t o_w1a = alloc(18 * 4 * 32);
  const size_t o_w1b = alloc(18 * 32 * 32);
  const size_t o_w2a = alloc(18 * 32 * 64);
  const size_t o_w2b = alloc(18 * 64 * 64);
  const size_t o_w3a = alloc(18 * 64 * 128);
  const size_t o_w3b = alloc(18 * 128 * 128);
  const size_t o_bs  = alloc(2048);
  const size_t o_hid = alloc((size_t)1280 * 2048);  // conv3b out == LSTM input rows
  const size_t o_gx  = alloc((size_t)1280 * 2048);  // x-projection gates
  const size_t o_R   = off;                         // overlapped region start

  // LSTM-phase scratch (used only AFTER the conv chunks are done)
  size_t loff = o_R;
  auto lalloc = [&loff](size_t n) { size_t r = loff; loff += (n + 255) & ~(size_t)255; return r; };
  const size_t o_g  = lalloc((size_t)256 * 2048);
  const size_t o_h  = lalloc(256 * 512);
  const size_t o_c  = lalloc(256 * 512);
  const size_t o_hs = lalloc((size_t)1280 * 512);
  const size_t o_z  = lalloc((size_t)1280 * 512);

  // conv-phase chunk scratch (per batch-chunk, ping-pong), also starts at o_R
  const size_t XP_B = 34816;   // 16*16*34*4
  const size_t A_B  = 261120;  // 15*16*34*32  (max of conv1a/2a/3a outputs)
  const size_t B_B  = 64512;   // 14*8*18*32   (max of conv1b/2b outputs)
  const size_t PER_B = XP_B + A_B + B_B;

  const size_t ws_floats = ws_size / sizeof(float);
  const size_t avail = (ws_floats > o_R) ? (ws_floats - o_R) : 0;
  int CB = 256;
  while (CB > 1 && (size_t)CB * PER_B > avail) CB >>= 1;
  const int nchunks = 256 / CB;

  const size_t o_xp = o_R;
  const size_t o_A  = o_xp + (size_t)CB * XP_B;
  const size_t o_B  = o_A  + (size_t)CB * A_B;

  auto nblk = [](long long n) { return (unsigned)((n + 255) / 256); };

  // ---------------- prep ----------------
  wtrans_kernel<<<nblk(18 * 4 * 32), 256, 0, stream>>>(w1a, ws + o_w1a, 4, 32, 1.f / 255.f, 18 * 4 * 32);
  wtrans_kernel<<<nblk(18 * 32 * 32), 256, 0, stream>>>(w1b, ws + o_w1b, 32, 32, 1.f, 18 * 32 * 32);
  wtrans_kernel<<<nblk(18 * 32 * 64), 256, 0, stream>>>(w2a, ws + o_w2a, 32, 64, 1.f / 255.f, 18 * 32 * 64);
  wtrans_kernel<<<nblk(18 * 64 * 64), 256, 0, stream>>>(w2b, ws + o_w2b, 64, 64, 1.f, 18 * 64 * 64);
  wtrans_kernel<<<nblk(18 * 64 * 128), 256, 0, stream>>>(w3a, ws + o_w3a, 64, 128, 1.f / 255.f, 18 * 64 * 128);
  wtrans_kernel<<<nblk(18 * 128 * 128), 256, 0, stream>>>(w3b, ws + o_w3b, 128, 128, 1.f, 18 * 128 * 128);
  bsum_kernel<<<8, 256, 0, stream>>>(b_ih, b_hh, ws + o_bs);

  // ---------------- conv chain, chunked over batch ----------------
  for (int c = 0; c < nchunks; ++c) {
    const int b0 = c * CB;
    pad_x_kernel<<<nblk((long long)CB * 16 * 16 * 34), 256, 0, stream>>>(
        x + (size_t)b0 * 16 * 16 * 32 * 4, ws + o_xp, CB * 16 * 16 * 34);
    conv1a_lds<<<CB * 15, 256, 0, stream>>>(
        ws + o_xp, ws + o_w1a, b1a, ws + o_A, CB);
    conv3d_relu<32, 32, 2, 4, false><<<nblk((long long)CB * 14 * 8 * 4 * 8), 256, 0, stream>>>(
        ws + o_A, ws + o_w1b, b1b, ws + o_B, CB, 15, 16, 32, 14, 8, 16);
    conv3d_relu<32, 64, 1, 4, false><<<nblk((long long)CB * 13 * 8 * 4 * 16), 256, 0, stream>>>(
        ws + o_B, ws + o_w2a, b2a, ws + o_A, CB, 14, 8, 16, 13, 8, 16);
    conv3d_relu<64, 64, 2, 4, false><<<nblk((long long)CB * 12 * 4 * 2 * 16), 256, 0, stream>>>(
        ws + o_A, ws + o_w2b, b2b, ws + o_B, CB, 13, 8, 16, 12, 4, 8);
    conv3d_relu<64, 128, 1, 4, false><<<nblk((long long)CB * 11 * 4 * 2 * 32), 256, 0, stream>>>(
        ws + o_B, ws + o_w3a, b3a, ws + o_A, CB, 12, 4, 8, 11, 4, 8);
    conv3d_relu<128, 128, 2, 4, true><<<nblk((long long)CB * 10 * 2 * 1 * 32), 256, 0, stream>>>(
        ws + o_A, ws + o_w3b, b3b, ws + o_hid + (size_t)b0 * 10240, CB, 11, 4, 8, 10, 2, 4);
  }
  // ws+o_hid now holds "hidden" = (1280, 2048) row-major (faithful reshape free)

  // x-projection for all 5 steps: gatesx = hidden @ W_ih^T + (b_ih + b_hh)
  gemm_nt<<<dim3(2048 / 64, 1280 / 64), 256, 0, stream>>>(
      ws + o_hid, W_ih, nullptr, ws + o_bs, ws + o_gx, 1280, 2048, 2048, 0, nullptr);

  // ---------------- recurrent steps (mask fused into GEMM + cell) ----------
  for (int l = 0; l < 5; ++l) {
    const float* hsrc = (l == 0) ? h0 : ws + o_h;
    const float* csrc = (l == 0) ? c0 : ws + o_c;
    gemm_nt<<<dim3(2048 / 64, 256 / 64), 256, 0, stream>>>(
        hsrc, W_hh, ws + o_gx + (size_t)l * 256 * 2048, nullptr,
        ws + o_g, 256, 2048, 512, 0, done + (size_t)l * 256);
    lstm_cell<<<512, 256, 0, stream>>>(
        ws + o_g, csrc, done + (size_t)l * 256,
        ws + o_hs + (size_t)l * 256 * 512, ws + o_h, ws + o_c,
        (l == 4) ? outp + 6400 : nullptr,
        (l == 4) ? outp + 6400 + 256 * 512 : nullptr);
  }

  // ---------------- heads ----------------
  gemm_nt<<<dim3(512 / 64, 1280 / 64), 256, 0, stream>>>(
      ws + o_hs, fc1w, nullptr, fc1b, ws + o_z, 1280, 512, 512, 1, nullptr);
  fc2_kernel<<<nblk(1280 * 5), 256, 0, stream>>>(ws + o_z, fc2w, fc2b, outp);
}

// Round 8
// 2420.205 us; speedup vs baseline: 3.2681x; 1.1373x over previous
//
#include <hip/hip_runtime.h>
#include <cstddef>

// ---------------------------------------------------------------------------
// CNN(3 conv blocks) -> faithful reshape -> 5-step LSTM -> fc1(relu) -> fc2
// All fp32. Activations channels-last with x-only halo padding.
// Conv chain chunked over batch (CB from ws_size); conv3b writes NCDHW so its
// output IS the LSTM "hidden" matrix (1280x2048).
// conv3d v4: (kt,ky)-outer with 3kx*IC*OCT weight slice staged in LDS per
// stage; ic4-INNER input reads (full cache-line use; fixes v3's 4x HBM
// over-fetch on conv1b: 8 ic4 passes x half-lines = 1.07GB vs 267MB input).
// OCT tiles oc across gridDim.y so big layers' stage fits LDS at 3 blk/CU.
// ---------------------------------------------------------------------------

// x chunk: (CB,16,16,32,4) -> xp: (CB,16,16,34,4) with x-halo zeros
__global__ __launch_bounds__(256) void pad_x_kernel(
    const float* __restrict__ x, float* __restrict__ xp, int total)
{
  int e = blockIdx.x * 256 + threadIdx.x;           // one float4 (ic) per thread
  if (e >= total) return;
  int xs = e % 34; int r = e / 34;
  float4 v = make_float4(0.f, 0.f, 0.f, 0.f);
  if (xs >= 1 && xs <= 32) {
    v = *reinterpret_cast<const float4*>(x + ((size_t)r * 32 + (xs - 1)) * 4);
  }
  *reinterpret_cast<float4*>(xp + (size_t)e * 4) = v;
}

// w: (OC,IC,2,3,3) -> wt: (k=kt*9+ky*3+kx, ic, oc), optional scale (folds /255)
__global__ __launch_bounds__(256) void wtrans_kernel(
    const float* __restrict__ w, float* __restrict__ wt,
    int IC, int OC, float scale, int total)
{
  int e = blockIdx.x * 256 + threadIdx.x;
  if (e >= total) return;
  int oc = e % OC; int t = e / OC; int ic = t % IC; int k = t / IC; // k in [0,18)
  int kt = k / 9; int r9 = k % 9; int ky = r9 / 3; int kx = r9 % 3;
  wt[e] = w[((((size_t)oc * IC + ic) * 2 + kt) * 3 + ky) * 3 + kx] * scale;
}

__global__ __launch_bounds__(256) void bsum_kernel(
    const float* __restrict__ a, const float* __restrict__ b, float* __restrict__ o)
{
  int e = blockIdx.x * 256 + threadIdx.x;
  if (e < 2048) o[e] = a[e] + b[e];
}

#define FMA4(A, S, W)                  \
  A.x = fmaf((S), (W).x, A.x);         \
  A.y = fmaf((S), (W).y, A.y);         \
  A.z = fmaf((S), (W).z, A.z);         \
  A.w = fmaf((S), (W).w, A.w)

// ---------------- conv1a: LDS-staged, IC=4, OC=32, SP=1 ----------------------
__global__ __launch_bounds__(256, 2) void conv1a_lds(
    const float* __restrict__ in, const float* __restrict__ wt,
    const float* __restrict__ bias, float* __restrict__ out, int B)
{
  __shared__ float4 sIn[2][18][34];
  const int b = blockIdx.x / 15;
  const int t = blockIdx.x % 15;
  const int tid = threadIdx.x;

  const float4* in4 = reinterpret_cast<const float4*>(in);
  for (int e = tid; e < 1224; e += 256) {
    const int kt = e / 612, rem = e % 612;
    const int yy = rem / 34, xx = rem % 34;     // yy: 0..17 -> y = yy-1
    const int y = yy - 1;
    float4 v = make_float4(0.f, 0.f, 0.f, 0.f);
    if (y >= 0 && y < 16)
      v = in4[((size_t)(b * 16 + (t + kt)) * 16 + y) * 34 + xx];
    sIn[kt][yy][xx] = v;
  }
  __syncthreads();

  const int oc8 = (tid & 3) * 8;
  const int xq  = (tid >> 2) & 3;
  const int y   = tid >> 4;
  const int xg  = xq * 8;

  float4 acc[8][2];
  const float4 bv0 = *reinterpret_cast<const float4*>(bias + oc8);
  const float4 bv1 = *reinterpret_cast<const float4*>(bias + oc8 + 4);
  #pragma unroll
  for (int r = 0; r < 8; ++r) { acc[r][0] = bv0; acc[r][1] = bv1; }

  #pragma unroll
  for (int kt = 0; kt < 2; ++kt) {
    #pragma unroll
    for (int ky = 0; ky < 3; ++ky) {
      const float4* __restrict__ row = &sIn[kt][y + ky][xg];
      float4 xv[10];
      #pragma unroll
      for (int p = 0; p < 10; ++p) xv[p] = row[p];
      #pragma unroll
      for (int kx = 0; kx < 3; ++kx) {
        const float* __restrict__ wp = wt + ((kt * 9 + ky * 3 + kx) * 4) * 32 + oc8;
        const float4 w00 = *reinterpret_cast<const float4*>(wp);
        const float4 w01 = *reinterpret_cast<const float4*>(wp + 4);
        const float4 w10 = *reinterpret_cast<const float4*>(wp + 32);
        const float4 w11 = *reinterpret_cast<const float4*>(wp + 36);
        const float4 w20 = *reinterpret_cast<const float4*>(wp + 64);
        const float4 w21 = *reinterpret_cast<const float4*>(wp + 68);
        const float4 w30 = *reinterpret_cast<const float4*>(wp + 96);
        const float4 w31 = *reinterpret_cast<const float4*>(wp + 100);
        #pragma unroll
        for (int r = 0; r < 8; ++r) {
          const float4 iv = xv[r + kx];
          FMA4(acc[r][0], iv.x, w00); FMA4(acc[r][1], iv.x, w01);
          FMA4(acc[r][0], iv.y, w10); FMA4(acc[r][1], iv.y, w11);
          FMA4(acc[r][0], iv.z, w20); FMA4(acc[r][1], iv.z, w21);
          FMA4(acc[r][0], iv.w, w30); FMA4(acc[r][1], iv.w, w31);
        }
      }
    }
  }

  float* op = out + (((size_t)(b * 15 + t) * 16 + y) * 34 + xg + 1) * 32 + oc8;
  const float4 z4 = make_float4(0.f, 0.f, 0.f, 0.f);
  #pragma unroll
  for (int r = 0; r < 8; ++r) {
    #pragma unroll
    for (int q = 0; q < 2; ++q) {
      acc[r][q].x = fmaxf(acc[r][q].x, 0.f);
      acc[r][q].y = fmaxf(acc[r][q].y, 0.f);
      acc[r][q].z = fmaxf(acc[r][q].z, 0.f);
      acc[r][q].w = fmaxf(acc[r][q].w, 0.f);
      *reinterpret_cast<float4*>(op + (size_t)r * 32 + q * 4) = acc[r][q];
    }
  }
  if (xg == 0) {
    *reinterpret_cast<float4*>(op - 32) = z4;
    *reinterpret_cast<float4*>(op - 28) = z4;
  }
  if (xg == 24) {
    *reinterpret_cast<float4*>(op + (size_t)8 * 32) = z4;
    *reinterpret_cast<float4*>(op + (size_t)8 * 32 + 4) = z4;
  }
}

// ---------------- direct conv v4: (kt,ky)-outer LDS weights, ic4-inner -------
// input : (B, Ti, Hi, Wi+2, IC) channels-last, x-halo padded
// output: (B, To, Ho, Wo+2, OC) channels-last, x-halo padded, or NCDHW
// weights: (18, IC, OC), bias: (OC). ReLU fused.
// Block: 256 threads = (OCT/4 oc-quads) x (256/(OCT/4) spatial units of RX x).
// gridDim.y tiles oc in OCT chunks. Per (kt,ky): stage 3kx*IC*OCT weights in
// LDS; inner ic4 loop reads input with full cache-line utilization.
template<int IC, int OC, int OCT, int SP, int RX, bool OUT_NCDHW>
__global__ __launch_bounds__(256) void conv3d_v4(
    const float* __restrict__ in, const float* __restrict__ wt,
    const float* __restrict__ bias, float* __restrict__ out,
    int B, int Ti, int Hi, int Wi, int To, int Ho, int Wo)
{
  constexpr int NOCT = OCT / 4;           // oc-quads per block
  constexpr int SPT  = 256 / NOCT;        // spatial units per block
  constexpr int NXW  = (RX - 1) * SP + 3; // input float4s per (kt,ky) window
  __shared__ float sW[3 * IC * OCT];
  const int tid  = threadIdx.x;
  const int oc4i = tid % NOCT;
  const int su   = tid / NOCT;
  const int oc0  = blockIdx.y * OCT;

  const int WT = Wo / RX;
  const long long u = (long long)blockIdx.x * SPT + su;
  const int xt = (int)(u % WT);
  const int y  = (int)((u / WT) % Ho);
  const int t  = (int)((u / ((long long)WT * Ho)) % To);
  int b        = (int)(u / ((long long)WT * Ho * To));
  const bool active = (b < B);
  if (!active) b = 0;
  const int xg  = xt * RX;
  const int Wis = Wi + 2;

  float4 acc[RX];
  const float4 bv = *reinterpret_cast<const float4*>(bias + oc0 + oc4i * 4);
  #pragma unroll
  for (int r = 0; r < RX; ++r) acc[r] = bv;

  const float4* wt4 = reinterpret_cast<const float4*>(wt);
  float4* sW4 = reinterpret_cast<float4*>(sW);

  #pragma unroll
  for (int kt = 0; kt < 2; ++kt) {
    #pragma unroll
    for (int ky = 0; ky < 3; ++ky) {
      __syncthreads();  // previous stage consumed
      // stage wt[(kt*3+ky)*3 + kx, ic, oc0..oc0+OCT) -> sW[kx][ic][OCT]
      for (int e = tid; e < 3 * IC * NOCT; e += 256) {
        const int kx = e / (IC * NOCT);
        const int rm = e % (IC * NOCT);
        const int ic = rm / NOCT;
        const int j4 = rm % NOCT;
        sW4[e] = wt4[((size_t)(((kt * 3 + ky) * 3 + kx) * IC) + ic) * (OC / 4)
                     + (oc0 / 4 + j4)];
      }
      __syncthreads();

      const int iy = y * SP + ky - 1;
      if (!active || iy < 0 || iy >= Hi) continue;  // barriers at loop top: safe
      const float* __restrict__ inrow =
          in + (size_t)((b * Ti + (t + kt)) * Hi + iy) * (size_t)(Wis * IC)
             + (size_t)(xg * SP) * IC;
      for (int ic4 = 0; ic4 < IC / 4; ++ic4) {
        float4 xv[NXW];
        #pragma unroll
        for (int p = 0; p < NXW; ++p)
          xv[p] = *reinterpret_cast<const float4*>(inrow + (size_t)p * IC + ic4 * 4);
        #pragma unroll
        for (int kx = 0; kx < 3; ++kx) {
          const float* __restrict__ wp = sW + ((size_t)kx * IC + ic4 * 4) * OCT + oc4i * 4;
          const float4 w0 = *reinterpret_cast<const float4*>(wp);
          const float4 w1 = *reinterpret_cast<const float4*>(wp + OCT);
          const float4 w2 = *reinterpret_cast<const float4*>(wp + 2 * OCT);
          const float4 w3 = *reinterpret_cast<const float4*>(wp + 3 * OCT);
          #pragma unroll
          for (int r = 0; r < RX; ++r) {
            const float4 iv = xv[r * SP + kx];
            FMA4(acc[r], iv.x, w0);
            FMA4(acc[r], iv.y, w1);
            FMA4(acc[r], iv.z, w2);
            FMA4(acc[r], iv.w, w3);
          }
        }
      }
    }
  }

  if (!active) return;

  #pragma unroll
  for (int r = 0; r < RX; ++r) {
    acc[r].x = fmaxf(acc[r].x, 0.0f);
    acc[r].y = fmaxf(acc[r].y, 0.0f);
    acc[r].z = fmaxf(acc[r].z, 0.0f);
    acc[r].w = fmaxf(acc[r].w, 0.0f);
  }

  if constexpr (OUT_NCDHW) {
    const size_t plane = (size_t)To * Ho * Wo;
    float* op = out + ((((size_t)b * OC + oc0 + oc4i * 4) * To + t) * Ho + y) * Wo + xg;
    #pragma unroll
    for (int i = 0; i < 4; ++i) {
      #pragma unroll
      for (int r = 0; r < RX; ++r)
        op[(size_t)i * plane + r] = ((const float*)&acc[r])[i];
    }
  } else {
    float* op = out + (((size_t)(b * To + t) * Ho + y) * (Wo + 2) + xg + 1) * OC
                    + oc0 + oc4i * 4;
    #pragma unroll
    for (int r = 0; r < RX; ++r)
      *reinterpret_cast<float4*>(op + (size_t)r * OC) = acc[r];
    const float4 z4 = make_float4(0.f, 0.f, 0.f, 0.f);
    if (xg == 0)        *reinterpret_cast<float4*>(op - OC) = z4;              // x=0
    if (xg + RX == Wo)  *reinterpret_cast<float4*>(op + (size_t)RX * OC) = z4; // x=Wo+1
  }
}

// ---------------- fp32 tiled GEMM: C = act(diag(1-Amask)*A * B^T + D + bias) --
__global__ __launch_bounds__(256) void gemm_nt(
    const float* __restrict__ A, const float* __restrict__ Bm,
    const float* __restrict__ D, const float* __restrict__ bias,
    float* __restrict__ C, int M, int N, int K, int relu,
    const float* __restrict__ Amask)
{
  __shared__ float As[16][68];
  __shared__ float Bs[16][68];
  const int tid = threadIdx.x;
  const int kk = tid & 15, rr = tid >> 4;   // load mapping
  const int tx = tid & 15, ty = tid >> 4;   // compute mapping
  const int m0 = blockIdx.y * 64, n0 = blockIdx.x * 64;

  float acc[4][4];
  #pragma unroll
  for (int i = 0; i < 4; ++i)
    #pragma unroll
    for (int j = 0; j < 4; ++j) acc[i][j] = 0.f;

  for (int k0 = 0; k0 < K; k0 += 16) {
    #pragma unroll
    for (int p = 0; p < 4; ++p) {
      const int m = m0 + rr + p * 16;
      const float s = Amask ? (1.f - Amask[m]) : 1.f;
      As[kk][rr + p * 16] = A[(size_t)m * K + (k0 + kk)] * s;
      Bs[kk][rr + p * 16] = Bm[(size_t)(n0 + rr + p * 16) * K + (k0 + kk)];
    }
    __syncthreads();
    #pragma unroll
    for (int k = 0; k < 16; ++k) {
      const float4 av = *reinterpret_cast<const float4*>(&As[k][ty * 4]);
      const float4 bv = *reinterpret_cast<const float4*>(&Bs[k][tx * 4]);
      const float a_[4] = {av.x, av.y, av.z, av.w};
      const float b_[4] = {bv.x, bv.y, bv.z, bv.w};
      #pragma unroll
      for (int i = 0; i < 4; ++i)
        #pragma unroll
        for (int j = 0; j < 4; ++j)
          acc[i][j] = fmaf(a_[i], b_[j], acc[i][j]);
    }
    __syncthreads();
  }

  #pragma unroll
  for (int i = 0; i < 4; ++i) {
    const int m = m0 + ty * 4 + i;
    const int n = n0 + tx * 4;
    float4 v = make_float4(acc[i][0], acc[i][1], acc[i][2], acc[i][3]);
    if (D) {
      const float4 d4 = *reinterpret_cast<const float4*>(&D[(size_t)m * N + n]);
      v.x += d4.x; v.y += d4.y; v.z += d4.z; v.w += d4.w;
    }
    if (bias) {
      const float4 b4 = *reinterpret_cast<const float4*>(&bias[n]);
      v.x += b4.x; v.y += b4.y; v.z += b4.z; v.w += b4.w;
    }
    if (relu) {
      v.x = fmaxf(v.x, 0.f); v.y = fmaxf(v.y, 0.f);
      v.z = fmaxf(v.z, 0.f); v.w = fmaxf(v.w, 0.f);
    }
    *reinterpret_cast<float4*>(&C[(size_t)m * N + n]) = v;
  }
}

// ---------------- LSTM cell (mask fused: cm = c_prev * (1-done)) -------------
__global__ __launch_bounds__(256) void lstm_cell(
    const float* __restrict__ gates, const float* __restrict__ c_prev,
    const float* __restrict__ done_l,
    float* __restrict__ hs_l, float* __restrict__ h_buf, float* __restrict__ c_buf,
    float* __restrict__ hT, float* __restrict__ cT)
{
  int e = blockIdx.x * 256 + threadIdx.x;
  if (e >= 256 * 512) return;
  const int b = e >> 9, u = e & 511;
  const float* gr = gates + (size_t)b * 2048;
  float i = gr[u], f = gr[512 + u], g = gr[1024 + u], o = gr[1536 + u];
  i = 1.f / (1.f + expf(-i));
  f = 1.f / (1.f + expf(-f));
  o = 1.f / (1.f + expf(-o));
  g = tanhf(g);
  const float cm = c_prev[e] * (1.f - done_l[b]);
  const float cn = f * cm + i * g;
  const float hn = o * tanhf(cn);
  hs_l[e] = hn; h_buf[e] = hn; c_buf[e] = cn;
  if (hT) { hT[e] = hn; cT[e] = cn; }
}

// logits (1280,5) = z (1280,512) @ fc2_w^T (512,5) + fc2_b
__global__ __launch_bounds__(256) void fc2_kernel(
    const float* __restrict__ z, const float* __restrict__ w,
    const float* __restrict__ b, float* __restrict__ out)
{
  int e = blockIdx.x * 256 + threadIdx.x;
  if (e >= 1280 * 5) return;
  const int n = e % 5, m = e / 5;
  const float* zr = z + (size_t)m * 512;
  const float* wr = w + (size_t)n * 512;
  float acc = b[n];
  for (int k = 0; k < 512; k += 4) {
    const float4 zv = *reinterpret_cast<const float4*>(zr + k);
    const float4 wv = *reinterpret_cast<const float4*>(wr + k);
    acc += zv.x * wv.x + zv.y * wv.y + zv.z * wv.z + zv.w * wv.w;
  }
  out[e] = acc;
}

// ---------------- host ----------------

extern "C" void kernel_launch(void* const* d_in, const int* in_sizes, int n_in,
                              void* d_out, int out_size, void* d_ws, size_t ws_size,
                              hipStream_t stream)
{
  const float* x    = (const float*)d_in[0];
  const float* done = (const float*)d_in[1];
  const float* h0   = (const float*)d_in[2];
  const float* c0   = (const float*)d_in[3];
  const float* w1a = (const float*)d_in[4];  const float* b1a = (const float*)d_in[5];
  const float* w1b = (const float*)d_in[6];  const float* b1b = (const float*)d_in[7];
  const float* w2a = (const float*)d_in[8];  const float* b2a = (const float*)d_in[9];
  const float* w2b = (const float*)d_in[10]; const float* b2b = (const float*)d_in[11];
  const float* w3a = (const float*)d_in[12]; const float* b3a = (const float*)d_in[13];
  const float* w3b = (const float*)d_in[14]; const float* b3b = (const float*)d_in[15];
  const float* W_ih = (const float*)d_in[16];
  const float* W_hh = (const float*)d_in[17];
  const float* b_ih = (const float*)d_in[18];
  const float* b_hh = (const float*)d_in[19];
  const float* fc1w = (const float*)d_in[20]; const float* fc1b = (const float*)d_in[21];
  const float* fc2w = (const float*)d_in[22]; const float* fc2b = (const float*)d_in[23];

  float* ws = (float*)d_ws;
  float* outp = (float*)d_out;
  (void)in_sizes; (void)n_in; (void)out_size;

  // ---------------- workspace layout (floats, all sizes 256-aligned) --------
  size_t off = 0;
  auto alloc = [&off](size_t n) { size_t r = off; off += (n + 255) & ~(size_t)255; return r; };
  const size_t o_w1a = alloc(18 * 4 * 32);
  const size_t o_w1b = alloc(18 * 32 * 32);
  const size_t o_w2a = alloc(18 * 32 * 64);
  const size_t o_w2b = alloc(18 * 64 * 64);
  const size_t o_w3a = alloc(18 * 64 * 128);
  const size_t o_w3b = alloc(18 * 128 * 128);
  const size_t o_bs  = alloc(2048);
  const size_t o_hid = alloc((size_t)1280 * 2048);  // conv3b out == LSTM input rows
  const size_t o_gx  = alloc((size_t)1280 * 2048);  // x-projection gates
  const size_t o_R   = off;                         // overlapped region start

  // LSTM-phase scratch (used only AFTER the conv chunks are done)
  size_t loff = o_R;
  auto lalloc = [&loff](size_t n) { size_t r = loff; loff += (n + 255) & ~(size_t)255; return r; };
  const size_t o_g  = lalloc((size_t)256 * 2048);
  const size_t o_h  = lalloc(256 * 512);
  const size_t o_c  = lalloc(256 * 512);
  const size_t o_hs = lalloc((size_t)1280 * 512);
  const size_t o_z  = lalloc((size_t)1280 * 512);

  // conv-phase chunk scratch (per batch-chunk, ping-pong), also starts at o_R
  const size_t XP_B = 34816;   // 16*16*34*4
  const size_t A_B  = 261120;  // 15*16*34*32  (max of conv1a/2a/3a outputs)
  const size_t B_B  = 64512;   // 14*8*18*32   (max of conv1b/2b outputs)
  const size_t PER_B = XP_B + A_B + B_B;

  const size_t ws_floats = ws_size / sizeof(float);
  const size_t avail = (ws_floats > o_R) ? (ws_floats - o_R) : 0;
  int CB = 256;
  while (CB > 1 && (size_t)CB * PER_B > avail) CB >>= 1;
  const int nchunks = 256 / CB;

  const size_t o_xp = o_R;
  const size_t o_A  = o_xp + (size_t)CB * XP_B;
  const size_t o_B  = o_A  + (size_t)CB * A_B;

  auto nblk = [](long long n) { return (unsigned)((n + 255) / 256); };
  auto ublk = [](long long units, int spt) { return (unsigned)((units + spt - 1) / spt); };

  // ---------------- prep ----------------
  wtrans_kernel<<<nblk(18 * 4 * 32), 256, 0, stream>>>(w1a, ws + o_w1a, 4, 32, 1.f / 255.f, 18 * 4 * 32);
  wtrans_kernel<<<nblk(18 * 32 * 32), 256, 0, stream>>>(w1b, ws + o_w1b, 32, 32, 1.f, 18 * 32 * 32);
  wtrans_kernel<<<nblk(18 * 32 * 64), 256, 0, stream>>>(w2a, ws + o_w2a, 32, 64, 1.f / 255.f, 18 * 32 * 64);
  wtrans_kernel<<<nblk(18 * 64 * 64), 256, 0, stream>>>(w2b, ws + o_w2b, 64, 64, 1.f, 18 * 64 * 64);
  wtrans_kernel<<<nblk(18 * 64 * 128), 256, 0, stream>>>(w3a, ws + o_w3a, 64, 128, 1.f / 255.f, 18 * 64 * 128);
  wtrans_kernel<<<nblk(18 * 128 * 128), 256, 0, stream>>>(w3b, ws + o_w3b, 128, 128, 1.f, 18 * 128 * 128);
  bsum_kernel<<<8, 256, 0, stream>>>(b_ih, b_hh, ws + o_bs);

  // ---------------- conv chain, chunked over batch ----------------
  for (int c = 0; c < nchunks; ++c) {
    const int b0 = c * CB;
    pad_x_kernel<<<nblk((long long)CB * 16 * 16 * 34), 256, 0, stream>>>(
        x + (size_t)b0 * 16 * 16 * 32 * 4, ws + o_xp, CB * 16 * 16 * 34);
    conv1a_lds<<<CB * 15, 256, 0, stream>>>(
        ws + o_xp, ws + o_w1a, b1a, ws + o_A, CB);
    // conv1b: OCT=32 -> SPT=32 ; units = CB*14*8*(16/4)
    conv3d_v4<32, 32, 32, 2, 4, false><<<dim3(ublk((long long)CB * 14 * 8 * 4, 32), 1), 256, 0, stream>>>(
        ws + o_A, ws + o_w1b, b1b, ws + o_B, CB, 15, 16, 32, 14, 8, 16);
    // conv2a: OCT=64 -> SPT=16 ; units = CB*13*8*4
    conv3d_v4<32, 64, 64, 1, 4, false><<<dim3(ublk((long long)CB * 13 * 8 * 4, 16), 1), 256, 0, stream>>>(
        ws + o_B, ws + o_w2a, b2a, ws + o_A, CB, 14, 8, 16, 13, 8, 16);
    // conv2b: OCT=64 -> SPT=16 ; units = CB*12*4*2
    conv3d_v4<64, 64, 64, 2, 4, false><<<dim3(ublk((long long)CB * 12 * 4 * 2, 16), 1), 256, 0, stream>>>(
        ws + o_A, ws + o_w2b, b2b, ws + o_B, CB, 13, 8, 16, 12, 4, 8);
    // conv3a: OCT=64 -> SPT=16, grid.y=2 ; units = CB*11*4*2
    conv3d_v4<64, 128, 64, 1, 4, false><<<dim3(ublk((long long)CB * 11 * 4 * 2, 16), 2), 256, 0, stream>>>(
        ws + o_B, ws + o_w3a, b3a, ws + o_A, CB, 12, 4, 8, 11, 4, 8);
    // conv3b: OCT=32 -> SPT=32, grid.y=4 ; units = CB*10*2*1
    conv3d_v4<128, 128, 32, 2, 4, true><<<dim3(ublk((long long)CB * 10 * 2 * 1, 32), 4), 256, 0, stream>>>(
        ws + o_A, ws + o_w3b, b3b, ws + o_hid + (size_t)b0 * 10240, CB, 11, 4, 8, 10, 2, 4);
  }
  // ws+o_hid now holds "hidden" = (1280, 2048) row-major (faithful reshape free)

  // x-projection for all 5 steps: gatesx = hidden @ W_ih^T + (b_ih + b_hh)
  gemm_nt<<<dim3(2048 / 64, 1280 / 64), 256, 0, stream>>>(
      ws + o_hid, W_ih, nullptr, ws + o_bs, ws + o_gx, 1280, 2048, 2048, 0, nullptr);

  // ---------------- recurrent steps (mask fused into GEMM + cell) ----------
  for (int l = 0; l < 5; ++l) {
    const float* hsrc = (l == 0) ? h0 : ws + o_h;
    const float* csrc = (l == 0) ? c0 : ws + o_c;
    gemm_nt<<<dim3(2048 / 64, 256 / 64), 256, 0, stream>>>(
        hsrc, W_hh, ws + o_gx + (size_t)l * 256 * 2048, nullptr,
        ws + o_g, 256, 2048, 512, 0, done + (size_t)l * 256);
    lstm_cell<<<512, 256, 0, stream>>>(
        ws + o_g, csrc, done + (size_t)l * 256,
        ws + o_hs + (size_t)l * 256 * 512, ws + o_h, ws + o_c,
        (l == 4) ? outp + 6400 : nullptr,
        (l == 4) ? outp + 6400 + 256 * 512 : nullptr);
  }

  // ---------------- heads ----------------
  gemm_nt<<<dim3(512 / 64, 1280 / 64), 256, 0, stream>>>(
      ws + o_hs, fc1w, nullptr, fc1b, ws + o_z, 1280, 512, 512, 1, nullptr);
  fc2_kernel<<<nblk(1280 * 5), 256, 0, stream>>>(ws + o_z, fc2w, fc2b, outp);
}

// Round 9
// 2038.538 us; speedup vs baseline: 3.8799x; 1.1872x over previous
//
#include <hip/hip_runtime.h>
#include <cstddef>

// ---------------------------------------------------------------------------
// CNN(3 conv blocks) -> faithful reshape -> 5-step LSTM -> fc1(relu) -> fc2
// All fp32. Activations channels-last with x-only halo padding.
// Conv chain chunked over batch (CB from ws_size); conv3b writes NCDHW so its
// output IS the LSTM "hidden" matrix (1280x2048).
// conv3d v4: (kt,ky)-outer with 3kx*IC*OCT weight slice staged in LDS.
// gemm v2: double-buffered LDS ping-pong, float4 register prefetch, ONE
// barrier per 16-k tile (was 2), float4 staging loads (was 8 scalar VMEM).
// Measured motivation: gates GEMM 260us @ 26% fp32 peak, VALUBusy 35% —
// barrier/latency-bound, not BW/ALU-bound.
// ---------------------------------------------------------------------------

// x chunk: (CB,16,16,32,4) -> xp: (CB,16,16,34,4) with x-halo zeros
__global__ __launch_bounds__(256) void pad_x_kernel(
    const float* __restrict__ x, float* __restrict__ xp, int total)
{
  int e = blockIdx.x * 256 + threadIdx.x;           // one float4 (ic) per thread
  if (e >= total) return;
  int xs = e % 34; int r = e / 34;
  float4 v = make_float4(0.f, 0.f, 0.f, 0.f);
  if (xs >= 1 && xs <= 32) {
    v = *reinterpret_cast<const float4*>(x + ((size_t)r * 32 + (xs - 1)) * 4);
  }
  *reinterpret_cast<float4*>(xp + (size_t)e * 4) = v;
}

// w: (OC,IC,2,3,3) -> wt: (k=kt*9+ky*3+kx, ic, oc), optional scale (folds /255)
__global__ __launch_bounds__(256) void wtrans_kernel(
    const float* __restrict__ w, float* __restrict__ wt,
    int IC, int OC, float scale, int total)
{
  int e = blockIdx.x * 256 + threadIdx.x;
  if (e >= total) return;
  int oc = e % OC; int t = e / OC; int ic = t % IC; int k = t / IC; // k in [0,18)
  int kt = k / 9; int r9 = k % 9; int ky = r9 / 3; int kx = r9 % 3;
  wt[e] = w[((((size_t)oc * IC + ic) * 2 + kt) * 3 + ky) * 3 + kx] * scale;
}

__global__ __launch_bounds__(256) void bsum_kernel(
    const float* __restrict__ a, const float* __restrict__ b, float* __restrict__ o)
{
  int e = blockIdx.x * 256 + threadIdx.x;
  if (e < 2048) o[e] = a[e] + b[e];
}

#define FMA4(A, S, W)                  \
  A.x = fmaf((S), (W).x, A.x);         \
  A.y = fmaf((S), (W).y, A.y);         \
  A.z = fmaf((S), (W).z, A.z);         \
  A.w = fmaf((S), (W).w, A.w)

// ---------------- conv1a: LDS-staged, IC=4, OC=32, SP=1 ----------------------
__global__ __launch_bounds__(256, 2) void conv1a_lds(
    const float* __restrict__ in, const float* __restrict__ wt,
    const float* __restrict__ bias, float* __restrict__ out, int B)
{
  __shared__ float4 sIn[2][18][34];
  const int b = blockIdx.x / 15;
  const int t = blockIdx.x % 15;
  const int tid = threadIdx.x;

  const float4* in4 = reinterpret_cast<const float4*>(in);
  for (int e = tid; e < 1224; e += 256) {
    const int kt = e / 612, rem = e % 612;
    const int yy = rem / 34, xx = rem % 34;     // yy: 0..17 -> y = yy-1
    const int y = yy - 1;
    float4 v = make_float4(0.f, 0.f, 0.f, 0.f);
    if (y >= 0 && y < 16)
      v = in4[((size_t)(b * 16 + (t + kt)) * 16 + y) * 34 + xx];
    sIn[kt][yy][xx] = v;
  }
  __syncthreads();

  const int oc8 = (tid & 3) * 8;
  const int xq  = (tid >> 2) & 3;
  const int y   = tid >> 4;
  const int xg  = xq * 8;

  float4 acc[8][2];
  const float4 bv0 = *reinterpret_cast<const float4*>(bias + oc8);
  const float4 bv1 = *reinterpret_cast<const float4*>(bias + oc8 + 4);
  #pragma unroll
  for (int r = 0; r < 8; ++r) { acc[r][0] = bv0; acc[r][1] = bv1; }

  #pragma unroll
  for (int kt = 0; kt < 2; ++kt) {
    #pragma unroll
    for (int ky = 0; ky < 3; ++ky) {
      const float4* __restrict__ row = &sIn[kt][y + ky][xg];
      float4 xv[10];
      #pragma unroll
      for (int p = 0; p < 10; ++p) xv[p] = row[p];
      #pragma unroll
      for (int kx = 0; kx < 3; ++kx) {
        const float* __restrict__ wp = wt + ((kt * 9 + ky * 3 + kx) * 4) * 32 + oc8;
        const float4 w00 = *reinterpret_cast<const float4*>(wp);
        const float4 w01 = *reinterpret_cast<const float4*>(wp + 4);
        const float4 w10 = *reinterpret_cast<const float4*>(wp + 32);
        const float4 w11 = *reinterpret_cast<const float4*>(wp + 36);
        const float4 w20 = *reinterpret_cast<const float4*>(wp + 64);
        const float4 w21 = *reinterpret_cast<const float4*>(wp + 68);
        const float4 w30 = *reinterpret_cast<const float4*>(wp + 96);
        const float4 w31 = *reinterpret_cast<const float4*>(wp + 100);
        #pragma unroll
        for (int r = 0; r < 8; ++r) {
          const float4 iv = xv[r + kx];
          FMA4(acc[r][0], iv.x, w00); FMA4(acc[r][1], iv.x, w01);
          FMA4(acc[r][0], iv.y, w10); FMA4(acc[r][1], iv.y, w11);
          FMA4(acc[r][0], iv.z, w20); FMA4(acc[r][1], iv.z, w21);
          FMA4(acc[r][0], iv.w, w30); FMA4(acc[r][1], iv.w, w31);
        }
      }
    }
  }

  float* op = out + (((size_t)(b * 15 + t) * 16 + y) * 34 + xg + 1) * 32 + oc8;
  const float4 z4 = make_float4(0.f, 0.f, 0.f, 0.f);
  #pragma unroll
  for (int r = 0; r < 8; ++r) {
    #pragma unroll
    for (int q = 0; q < 2; ++q) {
      acc[r][q].x = fmaxf(acc[r][q].x, 0.f);
      acc[r][q].y = fmaxf(acc[r][q].y, 0.f);
      acc[r][q].z = fmaxf(acc[r][q].z, 0.f);
      acc[r][q].w = fmaxf(acc[r][q].w, 0.f);
      *reinterpret_cast<float4*>(op + (size_t)r * 32 + q * 4) = acc[r][q];
    }
  }
  if (xg == 0) {
    *reinterpret_cast<float4*>(op - 32) = z4;
    *reinterpret_cast<float4*>(op - 28) = z4;
  }
  if (xg == 24) {
    *reinterpret_cast<float4*>(op + (size_t)8 * 32) = z4;
    *reinterpret_cast<float4*>(op + (size_t)8 * 32 + 4) = z4;
  }
}

// ---------------- direct conv v4: (kt,ky)-outer LDS weights, ic4-inner -------
template<int IC, int OC, int OCT, int SP, int RX, bool OUT_NCDHW>
__global__ __launch_bounds__(256) void conv3d_v4(
    const float* __restrict__ in, const float* __restrict__ wt,
    const float* __restrict__ bias, float* __restrict__ out,
    int B, int Ti, int Hi, int Wi, int To, int Ho, int Wo)
{
  constexpr int NOCT = OCT / 4;           // oc-quads per block
  constexpr int SPT  = 256 / NOCT;        // spatial units per block
  constexpr int NXW  = (RX - 1) * SP + 3; // input float4s per (kt,ky) window
  __shared__ float sW[3 * IC * OCT];
  const int tid  = threadIdx.x;
  const int oc4i = tid % NOCT;
  const int su   = tid / NOCT;
  const int oc0  = blockIdx.y * OCT;

  const int WT = Wo / RX;
  const long long u = (long long)blockIdx.x * SPT + su;
  const int xt = (int)(u % WT);
  const int y  = (int)((u / WT) % Ho);
  const int t  = (int)((u / ((long long)WT * Ho)) % To);
  int b        = (int)(u / ((long long)WT * Ho * To));
  const bool active = (b < B);
  if (!active) b = 0;
  const int xg  = xt * RX;
  const int Wis = Wi + 2;

  float4 acc[RX];
  const float4 bv = *reinterpret_cast<const float4*>(bias + oc0 + oc4i * 4);
  #pragma unroll
  for (int r = 0; r < RX; ++r) acc[r] = bv;

  const float4* wt4 = reinterpret_cast<const float4*>(wt);
  float4* sW4 = reinterpret_cast<float4*>(sW);

  #pragma unroll
  for (int kt = 0; kt < 2; ++kt) {
    #pragma unroll
    for (int ky = 0; ky < 3; ++ky) {
      __syncthreads();  // previous stage consumed
      for (int e = tid; e < 3 * IC * NOCT; e += 256) {
        const int kx = e / (IC * NOCT);
        const int rm = e % (IC * NOCT);
        const int ic = rm / NOCT;
        const int j4 = rm % NOCT;
        sW4[e] = wt4[((size_t)(((kt * 3 + ky) * 3 + kx) * IC) + ic) * (OC / 4)
                     + (oc0 / 4 + j4)];
      }
      __syncthreads();

      const int iy = y * SP + ky - 1;
      if (!active || iy < 0 || iy >= Hi) continue;  // barriers at loop top: safe
      const float* __restrict__ inrow =
          in + (size_t)((b * Ti + (t + kt)) * Hi + iy) * (size_t)(Wis * IC)
             + (size_t)(xg * SP) * IC;
      for (int ic4 = 0; ic4 < IC / 4; ++ic4) {
        float4 xv[NXW];
        #pragma unroll
        for (int p = 0; p < NXW; ++p)
          xv[p] = *reinterpret_cast<const float4*>(inrow + (size_t)p * IC + ic4 * 4);
        #pragma unroll
        for (int kx = 0; kx < 3; ++kx) {
          const float* __restrict__ wp = sW + ((size_t)kx * IC + ic4 * 4) * OCT + oc4i * 4;
          const float4 w0 = *reinterpret_cast<const float4*>(wp);
          const float4 w1 = *reinterpret_cast<const float4*>(wp + OCT);
          const float4 w2 = *reinterpret_cast<const float4*>(wp + 2 * OCT);
          const float4 w3 = *reinterpret_cast<const float4*>(wp + 3 * OCT);
          #pragma unroll
          for (int r = 0; r < RX; ++r) {
            const float4 iv = xv[r * SP + kx];
            FMA4(acc[r], iv.x, w0);
            FMA4(acc[r], iv.y, w1);
            FMA4(acc[r], iv.z, w2);
            FMA4(acc[r], iv.w, w3);
          }
        }
      }
    }
  }

  if (!active) return;

  #pragma unroll
  for (int r = 0; r < RX; ++r) {
    acc[r].x = fmaxf(acc[r].x, 0.0f);
    acc[r].y = fmaxf(acc[r].y, 0.0f);
    acc[r].z = fmaxf(acc[r].z, 0.0f);
    acc[r].w = fmaxf(acc[r].w, 0.0f);
  }

  if constexpr (OUT_NCDHW) {
    const size_t plane = (size_t)To * Ho * Wo;
    float* op = out + ((((size_t)b * OC + oc0 + oc4i * 4) * To + t) * Ho + y) * Wo + xg;
    #pragma unroll
    for (int i = 0; i < 4; ++i) {
      #pragma unroll
      for (int r = 0; r < RX; ++r)
        op[(size_t)i * plane + r] = ((const float*)&acc[r])[i];
    }
  } else {
    float* op = out + (((size_t)(b * To + t) * Ho + y) * (Wo + 2) + xg + 1) * OC
                    + oc0 + oc4i * 4;
    #pragma unroll
    for (int r = 0; r < RX; ++r)
      *reinterpret_cast<float4*>(op + (size_t)r * OC) = acc[r];
    const float4 z4 = make_float4(0.f, 0.f, 0.f, 0.f);
    if (xg == 0)        *reinterpret_cast<float4*>(op - OC) = z4;              // x=0
    if (xg + RX == Wo)  *reinterpret_cast<float4*>(op + (size_t)RX * OC) = z4; // x=Wo+1
  }
}

// ---------------- fp32 GEMM v2: C = act(diag(1-Amask)*A * B^T + D + bias) ----
// A: (M,K) row-major, Bm: (N,K) row-major; D opt (M,N), bias opt (N).
// M,N multiples of 64; K multiple of 16.
// Double-buffered LDS, float4 register prefetch, one barrier per 16-k tile.
__global__ __launch_bounds__(256) void gemm_nt(
    const float* __restrict__ A, const float* __restrict__ Bm,
    const float* __restrict__ D, const float* __restrict__ bias,
    float* __restrict__ C, int M, int N, int K, int relu,
    const float* __restrict__ Amask)
{
  __shared__ float As[2][16][68];
  __shared__ float Bs[2][16][68];
  const int tid = threadIdx.x;
  const int row = tid >> 2;            // 0..63 (m or n within tile)
  const int kq  = tid & 3;             // k-quad within 16-k tile
  const int tx = tid & 15, ty = tid >> 4;   // compute mapping
  const int m0 = blockIdx.y * 64, n0 = blockIdx.x * 64;

  const float sA = Amask ? (1.f - Amask[m0 + row]) : 1.f;
  const float* __restrict__ Arow = A + (size_t)(m0 + row) * K + kq * 4;
  const float* __restrict__ Brow = Bm + (size_t)(n0 + row) * K + kq * 4;

  // prefetch tile 0
  float4 a_pf = *reinterpret_cast<const float4*>(Arow);
  float4 b_pf = *reinterpret_cast<const float4*>(Brow);

  float acc[4][4];
  #pragma unroll
  for (int i = 0; i < 4; ++i)
    #pragma unroll
    for (int j = 0; j < 4; ++j) acc[i][j] = 0.f;

  const int niter = K >> 4;
  for (int it = 0; it < niter; ++it) {
    const int cur = it & 1;
    // store prefetched tile into LDS[cur] ([k][m] layout; 2-way write alias = free)
    As[cur][kq * 4 + 0][row] = a_pf.x * sA;
    As[cur][kq * 4 + 1][row] = a_pf.y * sA;
    As[cur][kq * 4 + 2][row] = a_pf.z * sA;
    As[cur][kq * 4 + 3][row] = a_pf.w * sA;
    Bs[cur][kq * 4 + 0][row] = b_pf.x;
    Bs[cur][kq * 4 + 1][row] = b_pf.y;
    Bs[cur][kq * 4 + 2][row] = b_pf.z;
    Bs[cur][kq * 4 + 3][row] = b_pf.w;
    __syncthreads();
    if (it + 1 < niter) {      // prefetch next tile; latency hidden under compute
      a_pf = *reinterpret_cast<const float4*>(Arow + (size_t)(it + 1) * 16);
      b_pf = *reinterpret_cast<const float4*>(Brow + (size_t)(it + 1) * 16);
    }
    #pragma unroll
    for (int k = 0; k < 16; ++k) {
      const float4 av = *reinterpret_cast<const float4*>(&As[cur][k][ty * 4]);
      const float4 bv = *reinterpret_cast<const float4*>(&Bs[cur][k][tx * 4]);
      const float a_[4] = {av.x, av.y, av.z, av.w};
      const float b_[4] = {bv.x, bv.y, bv.z, bv.w};
      #pragma unroll
      for (int i = 0; i < 4; ++i)
        #pragma unroll
        for (int j = 0; j < 4; ++j)
          acc[i][j] = fmaf(a_[i], b_[j], acc[i][j]);
    }
    // no trailing barrier: next iter writes the OTHER buffer; the barrier at
    // the top of iter it+1 orders those writes against iter it's reads.
  }

  #pragma unroll
  for (int i = 0; i < 4; ++i) {
    const int m = m0 + ty * 4 + i;
    const int n = n0 + tx * 4;
    float4 v = make_float4(acc[i][0], acc[i][1], acc[i][2], acc[i][3]);
    if (D) {
      const float4 d4 = *reinterpret_cast<const float4*>(&D[(size_t)m * N + n]);
      v.x += d4.x; v.y += d4.y; v.z += d4.z; v.w += d4.w;
    }
    if (bias) {
      const float4 b4 = *reinterpret_cast<const float4*>(&bias[n]);
      v.x += b4.x; v.y += b4.y; v.z += b4.z; v.w += b4.w;
    }
    if (relu) {
      v.x = fmaxf(v.x, 0.f); v.y = fmaxf(v.y, 0.f);
      v.z = fmaxf(v.z, 0.f); v.w = fmaxf(v.w, 0.f);
    }
    *reinterpret_cast<float4*>(&C[(size_t)m * N + n]) = v;
  }
}

// ---------------- LSTM cell (mask fused: cm = c_prev * (1-done)) -------------
__global__ __launch_bounds__(256) void lstm_cell(
    const float* __restrict__ gates, const float* __restrict__ c_prev,
    const float* __restrict__ done_l,
    float* __restrict__ hs_l, float* __restrict__ h_buf, float* __restrict__ c_buf,
    float* __restrict__ hT, float* __restrict__ cT)
{
  int e = blockIdx.x * 256 + threadIdx.x;
  if (e >= 256 * 512) return;
  const int b = e >> 9, u = e & 511;
  const float* gr = gates + (size_t)b * 2048;
  float i = gr[u], f = gr[512 + u], g = gr[1024 + u], o = gr[1536 + u];
  i = 1.f / (1.f + expf(-i));
  f = 1.f / (1.f + expf(-f));
  o = 1.f / (1.f + expf(-o));
  g = tanhf(g);
  const float cm = c_prev[e] * (1.f - done_l[b]);
  const float cn = f * cm + i * g;
  const float hn = o * tanhf(cn);
  hs_l[e] = hn; h_buf[e] = hn; c_buf[e] = cn;
  if (hT) { hT[e] = hn; cT[e] = cn; }
}

// logits (1280,5) = z (1280,512) @ fc2_w^T (512,5) + fc2_b
__global__ __launch_bounds__(256) void fc2_kernel(
    const float* __restrict__ z, const float* __restrict__ w,
    const float* __restrict__ b, float* __restrict__ out)
{
  int e = blockIdx.x * 256 + threadIdx.x;
  if (e >= 1280 * 5) return;
  const int n = e % 5, m = e / 5;
  const float* zr = z + (size_t)m * 512;
  const float* wr = w + (size_t)n * 512;
  float acc = b[n];
  for (int k = 0; k < 512; k += 4) {
    const float4 zv = *reinterpret_cast<const float4*>(zr + k);
    const float4 wv = *reinterpret_cast<const float4*>(wr + k);
    acc += zv.x * wv.x + zv.y * wv.y + zv.z * wv.z + zv.w * wv.w;
  }
  out[e] = acc;
}

// ---------------- host ----------------

extern "C" void kernel_launch(void* const* d_in, const int* in_sizes, int n_in,
                              void* d_out, int out_size, void* d_ws, size_t ws_size,
                              hipStream_t stream)
{
  const float* x    = (const float*)d_in[0];
  const float* done = (const float*)d_in[1];
  const float* h0   = (const float*)d_in[2];
  const float* c0   = (const float*)d_in[3];
  const float* w1a = (const float*)d_in[4];  const float* b1a = (const float*)d_in[5];
  const float* w1b = (const float*)d_in[6];  const float* b1b = (const float*)d_in[7];
  const float* w2a = (const float*)d_in[8];  const float* b2a = (const float*)d_in[9];
  const float* w2b = (const float*)d_in[10]; const float* b2b = (const float*)d_in[11];
  const float* w3a = (const float*)d_in[12]; const float* b3a = (const float*)d_in[13];
  const float* w3b = (const float*)d_in[14]; const float* b3b = (const float*)d_in[15];
  const float* W_ih = (const float*)d_in[16];
  const float* W_hh = (const float*)d_in[17];
  const float* b_ih = (const float*)d_in[18];
  const float* b_hh = (const float*)d_in[19];
  const float* fc1w = (const float*)d_in[20]; const float* fc1b = (const float*)d_in[21];
  const float* fc2w = (const float*)d_in[22]; const float* fc2b = (const float*)d_in[23];

  float* ws = (float*)d_ws;
  float* outp = (float*)d_out;
  (void)in_sizes; (void)n_in; (void)out_size;

  // ---------------- workspace layout (floats, all sizes 256-aligned) --------
  size_t off = 0;
  auto alloc = [&off](size_t n) { size_t r = off; off += (n + 255) & ~(size_t)255; return r; };
  const size_t o_w1a = alloc(18 * 4 * 32);
  const size_t o_w1b = alloc(18 * 32 * 32);
  const size_t o_w2a = alloc(18 * 32 * 64);
  const size_t o_w2b = alloc(18 * 64 * 64);
  const size_t o_w3a = alloc(18 * 64 * 128);
  const size_t o_w3b = alloc(18 * 128 * 128);
  const size_t o_bs  = alloc(2048);
  const size_t o_hid = alloc((size_t)1280 * 2048);  // conv3b out == LSTM input rows
  const size_t o_gx  = alloc((size_t)1280 * 2048);  // x-projection gates
  const size_t o_R   = off;                         // overlapped region start

  // LSTM-phase scratch (used only AFTER the conv chunks are done)
  size_t loff = o_R;
  auto lalloc = [&loff](size_t n) { size_t r = loff; loff += (n + 255) & ~(size_t)255; return r; };
  const size_t o_g  = lalloc((size_t)256 * 2048);
  const size_t o_h  = lalloc(256 * 512);
  const size_t o_c  = lalloc(256 * 512);
  const size_t o_hs = lalloc((size_t)1280 * 512);
  const size_t o_z  = lalloc((size_t)1280 * 512);

  // conv-phase chunk scratch (per batch-chunk, ping-pong), also starts at o_R
  const size_t XP_B = 34816;   // 16*16*34*4
  const size_t A_B  = 261120;  // 15*16*34*32  (max of conv1a/2a/3a outputs)
  const size_t B_B  = 64512;   // 14*8*18*32   (max of conv1b/2b outputs)
  const size_t PER_B = XP_B + A_B + B_B;

  const size_t ws_floats = ws_size / sizeof(float);
  const size_t avail = (ws_floats > o_R) ? (ws_floats - o_R) : 0;
  int CB = 256;
  while (CB > 1 && (size_t)CB * PER_B > avail) CB >>= 1;
  const int nchunks = 256 / CB;

  const size_t o_xp = o_R;
  const size_t o_A  = o_xp + (size_t)CB * XP_B;
  const size_t o_B  = o_A  + (size_t)CB * A_B;

  auto nblk = [](long long n) { return (unsigned)((n + 255) / 256); };
  auto ublk = [](long long units, int spt) { return (unsigned)((units + spt - 1) / spt); };

  // ---------------- prep ----------------
  wtrans_kernel<<<nblk(18 * 4 * 32), 256, 0, stream>>>(w1a, ws + o_w1a, 4, 32, 1.f / 255.f, 18 * 4 * 32);
  wtrans_kernel<<<nblk(18 * 32 * 32), 256, 0, stream>>>(w1b, ws + o_w1b, 32, 32, 1.f, 18 * 32 * 32);
  wtrans_kernel<<<nblk(18 * 32 * 64), 256, 0, stream>>>(w2a, ws + o_w2a, 32, 64, 1.f / 255.f, 18 * 32 * 64);
  wtrans_kernel<<<nblk(18 * 64 * 64), 256, 0, stream>>>(w2b, ws + o_w2b, 64, 64, 1.f, 18 * 64 * 64);
  wtrans_kernel<<<nblk(18 * 64 * 128), 256, 0, stream>>>(w3a, ws + o_w3a, 64, 128, 1.f / 255.f, 18 * 64 * 128);
  wtrans_kernel<<<nblk(18 * 128 * 128), 256, 0, stream>>>(w3b, ws + o_w3b, 128, 128, 1.f, 18 * 128 * 128);
  bsum_kernel<<<8, 256, 0, stream>>>(b_ih, b_hh, ws + o_bs);

  // ---------------- conv chain, chunked over batch ----------------
  for (int c = 0; c < nchunks; ++c) {
    const int b0 = c * CB;
    pad_x_kernel<<<nblk((long long)CB * 16 * 16 * 34), 256, 0, stream>>>(
        x + (size_t)b0 * 16 * 16 * 32 * 4, ws + o_xp, CB * 16 * 16 * 34);
    conv1a_lds<<<CB * 15, 256, 0, stream>>>(
        ws + o_xp, ws + o_w1a, b1a, ws + o_A, CB);
    conv3d_v4<32, 32, 32, 2, 4, false><<<dim3(ublk((long long)CB * 14 * 8 * 4, 32), 1), 256, 0, stream>>>(
        ws + o_A, ws + o_w1b, b1b, ws + o_B, CB, 15, 16, 32, 14, 8, 16);
    conv3d_v4<32, 64, 64, 1, 4, false><<<dim3(ublk((long long)CB * 13 * 8 * 4, 16), 1), 256, 0, stream>>>(
        ws + o_B, ws + o_w2a, b2a, ws + o_A, CB, 14, 8, 16, 13, 8, 16);
    conv3d_v4<64, 64, 64, 2, 4, false><<<dim3(ublk((long long)CB * 12 * 4 * 2, 16), 1), 256, 0, stream>>>(
        ws + o_A, ws + o_w2b, b2b, ws + o_B, CB, 13, 8, 16, 12, 4, 8);
    conv3d_v4<64, 128, 64, 1, 4, false><<<dim3(ublk((long long)CB * 11 * 4 * 2, 16), 2), 256, 0, stream>>>(
        ws + o_B, ws + o_w3a, b3a, ws + o_A, CB, 12, 4, 8, 11, 4, 8);
    conv3d_v4<128, 128, 32, 2, 4, true><<<dim3(ublk((long long)CB * 10 * 2 * 1, 32), 4), 256, 0, stream>>>(
        ws + o_A, ws + o_w3b, b3b, ws + o_hid + (size_t)b0 * 10240, CB, 11, 4, 8, 10, 2, 4);
  }
  // ws+o_hid now holds "hidden" = (1280, 2048) row-major (faithful reshape free)

  // x-projection for all 5 steps: gatesx = hidden @ W_ih^T + (b_ih + b_hh)
  gemm_nt<<<dim3(2048 / 64, 1280 / 64), 256, 0, stream>>>(
      ws + o_hid, W_ih, nullptr, ws + o_bs, ws + o_gx, 1280, 2048, 2048, 0, nullptr);

  // ---------------- recurrent steps (mask fused into GEMM + cell) ----------
  for (int l = 0; l < 5; ++l) {
    const float* hsrc = (l == 0) ? h0 : ws + o_h;
    const float* csrc = (l == 0) ? c0 : ws + o_c;
    gemm_nt<<<dim3(2048 / 64, 256 / 64), 256, 0, stream>>>(
        hsrc, W_hh, ws + o_gx + (size_t)l * 256 * 2048, nullptr,
        ws + o_g, 256, 2048, 512, 0, done + (size_t)l * 256);
    lstm_cell<<<512, 256, 0, stream>>>(
        ws + o_g, csrc, done + (size_t)l * 256,
        ws + o_hs + (size_t)l * 256 * 512, ws + o_h, ws + o_c,
        (l == 4) ? outp + 6400 : nullptr,
        (l == 4) ? outp + 6400 + 256 * 512 : nullptr);
  }

  // ---------------- heads ----------------
  gemm_nt<<<dim3(512 / 64, 1280 / 64), 256, 0, stream>>>(
      ws + o_hs, fc1w, nullptr, fc1b, ws + o_z, 1280, 512, 512, 1, nullptr);
  fc2_kernel<<<nblk(1280 * 5), 256, 0, stream>>>(ws + o_z, fc2w, fc2b, outp);
}